// Round 9
// baseline (546.411 us; speedup 1.0000x reference)
//
#include <hip/hip_runtime.h>
#include <hip/hip_bf16.h>

typedef unsigned short u16;
typedef __attribute__((ext_vector_type(8))) short short8;
typedef __attribute__((ext_vector_type(4))) short short4v;
typedef __attribute__((ext_vector_type(4))) float f32x4;

#define NEGV -1000000000000000.0f

__device__ __forceinline__ u16 f2bf(float f) {
  unsigned u = __float_as_uint(f);
  unsigned r = (u + 0x7FFFu + ((u >> 16) & 1u)) >> 16;
  return (u16)r;
}
__device__ __forceinline__ float bf2f(u16 s) {
  return __uint_as_float(((unsigned)s) << 16);
}
__device__ __forceinline__ void lds16(const void* g, void* l) {
  __builtin_amdgcn_global_load_lds((const __attribute__((address_space(1))) void*)g,
                                   (__attribute__((address_space(3))) void*)l,
                                   16, 0, 0);
}

// ============ FUSED kernel: A/Bm GEMMs + products + final projection ========
// Grid (mtile 0..7, b 0..63), 512 thr (8 waves), 160KB LDS, 2 waves/SIMD.
// Per block: OA[512 o][128 c] fp32 accumulated over K=2048 (4 chunks x 4 dcol
// x 128). Pieces computed in-register from Sbar/Qo/Tt, products with Ct tile,
// bounced through LDS as swizzled bf16 B-operands. Wr staged per (chunk,ohalf).
__global__ __launch_bounds__(512, 2) void gemm_f(
    const u16* __restrict__ Sb, const u16* __restrict__ Qo,
    const u16* __restrict__ Tt, const u16* __restrict__ Ct,
    const u16* __restrict__ Wrb, float* __restrict__ out) {
  extern __shared__ u16 sh[];
  u16* S  = sh;            // 32KB Sbar tile [128c][128j]
  u16* R1 = sh + 16384;    // 32KB: Qo tile, later Wr rows 0-127 of half
  u16* R2 = sh + 32768;    // 32KB: Tt tile, later Wr rows 128-255 (contig w/ R1)
  u16* R3 = sh + 49152;    // 32KB piece [128c][128d]
  u16* R4 = sh + 65536;    // 32KB Ct tile [128c][128d]
  const int mt = blockIdx.x;
  const int b  = blockIdx.y;
  const int m0 = mt * 128;
  const int t = threadIdx.x;
  const int lane = t & 63;
  const int w = t >> 6;
  const int fro = lane & 15, hi = lane >> 4;
  const int srow4 = t >> 4;
  const int sslot = t & 15;
  const int o1 = (w >> 1) * 64;   // stage2 o-band (within 256-half)
  const int cb2 = (w & 1) * 64;   // stage2 c-band

#define STG32(gp, ld, lp)                                                     \
  {                                                                           \
    _Pragma("unroll") for (int ii = 0; ii < 4; ++ii) {                        \
      const int row_ = ii * 32 + srow4;                                       \
      lds16((gp) + (size_t)row_ * (ld) + ((sslot ^ (row_ & 7)) << 3),         \
            (u16*)(lp) + ii * 4096 + t * 8);                                  \
    }                                                                         \
  }
#define RDS(base, row, kslot)                                                 \
  (*(const short8*)&(base)[(size_t)(row) * 128 + (((kslot) ^ ((row) & 7)) << 3)])

  f32x4 OA[2][4][4] = {};  // [ohalf][o-frag][c-frag]

  STG32(Sb + (size_t)b * 131072 + (size_t)m0 * 128, 128, S);
  __syncthreads();

  for (int dcol = 0; dcol < 4; ++dcol) {
    // ---- stage Qo, Tt, Ct tiles for this dcol
    STG32(Qo + (size_t)b * 65536 + (size_t)(dcol * 128) * 128, 128, R1);
    STG32(Tt + (size_t)b * 65536 + (size_t)(dcol * 128) * 128, 128, R2);
    STG32(Ct + (size_t)b * 524288 + (size_t)m0 * 512 + dcol * 128, 512, R4);
    __syncthreads();

    // ---- stage1 pass T: ab = Sbar@Tt^T (16c/wave x 128d); piece3 = Ct*ab -> R3
    {
      f32x4 p[8] = {};
#pragma unroll
      for (int ks = 0; ks < 4; ++ks) {
        const short8 af = RDS(S, w * 16 + fro, ks * 4 + hi);
        short8 bf[8];
#pragma unroll
        for (int jd = 0; jd < 8; ++jd) bf[jd] = RDS(R2, jd * 16 + fro, ks * 4 + hi);
#pragma unroll
        for (int jd = 0; jd < 8; ++jd)
          p[jd] = __builtin_amdgcn_mfma_f32_16x16x32_bf16(af, bf[jd], p[jd], 0, 0, 0);
      }
#pragma unroll
      for (int jd = 0; jd < 8; ++jd)
#pragma unroll
        for (int g = 0; g < 4; ++g) {
          const int c = w * 16 + hi * 4 + g;
          const int d = jd * 16 + fro;
          const int a = c * 128 + (((d >> 3) ^ (c & 7)) << 3) + (d & 7);
          R3[a] = f2bf(p[jd][g] * bf2f(R4[a]));
        }
    }
    // ---- stage1 pass A: aa = Sbar@Qo^T (kept in regs through chunk loop)
    f32x4 paa[8] = {};
#pragma unroll
    for (int ks = 0; ks < 4; ++ks) {
      const short8 af = RDS(S, w * 16 + fro, ks * 4 + hi);
      short8 bf[8];
#pragma unroll
      for (int jd = 0; jd < 8; ++jd) bf[jd] = RDS(R1, jd * 16 + fro, ks * 4 + hi);
#pragma unroll
      for (int jd = 0; jd < 8; ++jd)
        paa[jd] = __builtin_amdgcn_mfma_f32_16x16x32_bf16(af, bf[jd], paa[jd], 0, 0, 0);
    }
    __syncthreads();  // piece3 visible; R1,R2 free for Wr staging

    // ---- chunks in order 3,0,1,2 (accumulation order is free)
#pragma unroll
    for (int cc = 0; cc < 4; ++cc) {
      const int ch = (cc == 0) ? 3 : cc - 1;
      if (ch == 1 || ch == 2) {
#pragma unroll
        for (int jd = 0; jd < 8; ++jd)
#pragma unroll
          for (int g = 0; g < 4; ++g) {
            const int c = w * 16 + hi * 4 + g;
            const int d = jd * 16 + fro;
            const int a = c * 128 + (((d >> 3) ^ (c & 7)) << 3) + (d & 7);
            R3[a] = f2bf(ch == 1 ? paa[jd][g] : paa[jd][g] * bf2f(R4[a]));
          }
      }
      const u16* Wp = Wrb + (size_t)ch * 512 + (size_t)dcol * 128;
      // Wr o-half 0 (rows 0..255) into R1||R2
      STG32(Wp, 2048, R1);
      STG32(Wp + (size_t)128 * 2048, 2048, R2);
      __syncthreads();
      const u16* Bp = (ch == 0) ? R4 : R3;
#pragma unroll
      for (int ks = 0; ks < 4; ++ks) {
        short8 af[4], bfr[4];
#pragma unroll
        for (int i = 0; i < 4; ++i) af[i] = RDS(R1, o1 + i * 16 + fro, ks * 4 + hi);
#pragma unroll
        for (int j = 0; j < 4; ++j) bfr[j] = RDS(Bp, cb2 + j * 16 + fro, ks * 4 + hi);
#pragma unroll
        for (int i = 0; i < 4; ++i)
#pragma unroll
          for (int j = 0; j < 4; ++j)
            OA[0][i][j] = __builtin_amdgcn_mfma_f32_16x16x32_bf16(
                af[i], bfr[j], OA[0][i][j], 0, 0, 0);
      }
      __syncthreads();
      // Wr o-half 1 (rows 256..511)
      STG32(Wp + (size_t)256 * 2048, 2048, R1);
      STG32(Wp + (size_t)384 * 2048, 2048, R2);
      __syncthreads();
#pragma unroll
      for (int ks = 0; ks < 4; ++ks) {
        short8 af[4], bfr[4];
#pragma unroll
        for (int i = 0; i < 4; ++i) af[i] = RDS(R1, o1 + i * 16 + fro, ks * 4 + hi);
#pragma unroll
        for (int j = 0; j < 4; ++j) bfr[j] = RDS(Bp, cb2 + j * 16 + fro, ks * 4 + hi);
#pragma unroll
        for (int i = 0; i < 4; ++i)
#pragma unroll
          for (int j = 0; j < 4; ++j)
            OA[1][i][j] = __builtin_amdgcn_mfma_f32_16x16x32_bf16(
                af[i], bfr[j], OA[1][i][j], 0, 0, 0);
      }
      __syncthreads();
    }
  }

  // ---- epilogue: out[b][o][c]
  float* ob = out + (size_t)b * 524288;
#pragma unroll
  for (int oh = 0; oh < 2; ++oh)
#pragma unroll
    for (int i = 0; i < 4; ++i)
#pragma unroll
      for (int j = 0; j < 4; ++j) {
        const int o = oh * 256 + o1 + i * 16 + hi * 4;
        const int c = m0 + cb2 + j * 16 + fro;
#pragma unroll
        for (int g = 0; g < 4; ++g)
          ob[(size_t)(o + g) * 1024 + c] = OA[oh][i][j][g];
      }
#undef STG32
#undef RDS
}

// ============ T-GEMM: C_un = EunT(128x1024) @ Corig(512x1024)^T, then
// Tt[b][d][j] = C_un[j][d] / csum[b][j]  (transposed scaled store) ===========
__global__ __launch_bounds__(256) void gemm_t(const u16* __restrict__ A,
                                              const u16* __restrict__ B,
                                              const float* __restrict__ csum,
                                              u16* __restrict__ Tt) {
  __shared__ u16 As[128 * 64];
  __shared__ u16 Bs[128 * 64];
  const int b = blockIdx.z;
  const int n0 = blockIdx.y * 128;
  const u16* Ab = A + (size_t)b * 131072;
  const u16* Bb = B + (size_t)b * 524288;
  const int t = threadIdx.x;
  const int lane = t & 63;
  const int w = t >> 6;
  const int wr = w >> 1, wc = w & 1;
  const int srow = lane >> 3;
  const int scol = (lane & 7) * 8;

  f32x4 acc[4][4] = {};

  for (int k0 = 0; k0 < 1024; k0 += 64) {
    __syncthreads();
#pragma unroll
    for (int qq = 0; qq < 4; ++qq) {
      const int q = w * 4 + qq;
      const int r = q * 8 + srow;
      lds16(Ab + (size_t)r * 1024 + k0 + scol, &As[q * 512]);
      lds16(Bb + (size_t)(n0 + r) * 1024 + k0 + scol, &Bs[q * 512]);
    }
    __syncthreads();
#pragma unroll
    for (int ks = 0; ks < 2; ++ks) {
      short8 af[4], bg[4];
      const int fro = lane & 15;
      const int k8 = ks * 32 + (lane >> 4) * 8;
#pragma unroll
      for (int i = 0; i < 4; ++i)
        af[i] = *(const short8*)&As[(wr * 64 + i * 16 + fro) * 64 + k8];
#pragma unroll
      for (int i = 0; i < 4; ++i)
        bg[i] = *(const short8*)&Bs[(wc * 64 + i * 16 + fro) * 64 + k8];
#pragma unroll
      for (int i = 0; i < 4; ++i)
#pragma unroll
        for (int j = 0; j < 4; ++j)
          acc[i][j] =
              __builtin_amdgcn_mfma_f32_16x16x32_bf16(af[i], bg[j], acc[i][j], 0, 0, 0);
    }
  }

  const int col = lane & 15;
  const int r4 = (lane >> 4) * 4;
#pragma unroll
  for (int i = 0; i < 4; ++i)
#pragma unroll
    for (int g = 0; g < 4; ++g) {
      const int rr = wr * 64 + i * 16 + r4 + g;  // j index
      const float inv = 1.f / csum[b * 128 + rr];
#pragma unroll
      for (int j = 0; j < 4; ++j) {
        const int cc = n0 + wc * 64 + j * 16 + col;  // d index
        Tt[(size_t)b * 65536 + (size_t)cc * 128 + rr] = f2bf(acc[i][j][g] * inv);
      }
    }
}

// ============ S-GEMM + fused dual softmax + transposed-Eun epilogue =========
// A operand is now compact Ct (B,1024,512), lda 512.
__global__ __launch_bounds__(256) void gemm_s(
    const u16* __restrict__ A, const u16* __restrict__ Bq,
    const float* __restrict__ cb, const float* __restrict__ qb,
    const float* __restrict__ cmask, const float* __restrict__ qmask,
    u16* __restrict__ Sbar, u16* __restrict__ EunT, float* __restrict__ csum) {
  __shared__ u16 As[128 * 64];
  __shared__ u16 Bs[128 * 64];
  __shared__ u16 Lt[128][136];
  __shared__ float rmaxs[2][128];
  __shared__ float rsums[2][128];
  __shared__ float cparts[2][128];
  const int b = blockIdx.z;
  const int m0 = blockIdx.x * 128;
  const u16* Ab = A + (size_t)b * 524288;
  const u16* Bb = Bq + (size_t)b * 65536;
  const int t = threadIdx.x;
  const int lane = t & 63;
  const int w = t >> 6;
  const int wr = w >> 1, wc = w & 1;
  const int srow = lane >> 3;
  const int scol = (lane & 7) * 8;

  f32x4 acc[4][4] = {};

  for (int k0 = 0; k0 < 512; k0 += 64) {
    __syncthreads();
#pragma unroll
    for (int qq = 0; qq < 4; ++qq) {
      const int q = w * 4 + qq;
      const int r = q * 8 + srow;
      lds16(Ab + (size_t)(m0 + r) * 512 + k0 + scol, &As[q * 512]);
      lds16(Bb + (size_t)r * 512 + k0 + scol, &Bs[q * 512]);
    }
    __syncthreads();
#pragma unroll
    for (int ks = 0; ks < 2; ++ks) {
      short8 af[4], bg[4];
      const int fro = lane & 15;
      const int k8 = ks * 32 + (lane >> 4) * 8;
#pragma unroll
      for (int i = 0; i < 4; ++i)
        af[i] = *(const short8*)&As[(wr * 64 + i * 16 + fro) * 64 + k8];
#pragma unroll
      for (int i = 0; i < 4; ++i)
        bg[i] = *(const short8*)&Bs[(wc * 64 + i * 16 + fro) * 64 + k8];
#pragma unroll
      for (int i = 0; i < 4; ++i)
#pragma unroll
        for (int j = 0; j < 4; ++j)
          acc[i][j] =
              __builtin_amdgcn_mfma_f32_16x16x32_bf16(af[i], bg[j], acc[i][j], 0, 0, 0);
    }
  }

  const int fro = lane & 15;
  const int hi = lane >> 4;
  float qv[4], qbv[4];
#pragma unroll
  for (int j = 0; j < 4; ++j) {
    const int cc = wc * 64 + j * 16 + fro;
    qv[j] = qmask[b * 128 + cc];
    qbv[j] = qb[b * 128 + cc];
  }
  float colp[4] = {0.f, 0.f, 0.f, 0.f};
#pragma unroll
  for (int i = 0; i < 4; ++i)
#pragma unroll
    for (int g = 0; g < 4; ++g) {
      const int rl = wr * 64 + i * 16 + hi * 4 + g;
      const float rb = cb[b * 1024 + m0 + rl];
      const float cv = cmask[b * 1024 + m0 + rl];
      const float coff = NEGV * (1.f - cv);
#pragma unroll
      for (int j = 0; j < 4; ++j) {
        const float v = acc[i][j][g] + rb + qbv[j];
        acc[i][j][g] = v;
        const float e = __expf(v * cv + coff);
        Lt[wc * 64 + j * 16 + fro][rl] = f2bf(e);
        colp[j] += e;
      }
    }
#pragma unroll
  for (int j = 0; j < 4; ++j) {
    colp[j] += __shfl_xor(colp[j], 16);
    colp[j] += __shfl_xor(colp[j], 32);
  }
  if (hi == 0)
#pragma unroll
    for (int j = 0; j < 4; ++j) cparts[wr][wc * 64 + j * 16 + fro] = colp[j];
  float rtmp[4][4];
#pragma unroll
  for (int i = 0; i < 4; ++i)
#pragma unroll
    for (int g = 0; g < 4; ++g) {
      float m = -3.4e38f;
#pragma unroll
      for (int j = 0; j < 4; ++j) {
        const float xm = acc[i][j][g] * qv[j] + NEGV * (1.f - qv[j]);
        acc[i][j][g] = xm;
        m = fmaxf(m, xm);
      }
#pragma unroll
      for (int o = 8; o; o >>= 1) m = fmaxf(m, __shfl_xor(m, o));
      rtmp[i][g] = m;
    }
  if (fro == 0)
#pragma unroll
    for (int i = 0; i < 4; ++i)
#pragma unroll
      for (int g = 0; g < 4; ++g)
        rmaxs[wc][wr * 64 + i * 16 + hi * 4 + g] = rtmp[i][g];
  __syncthreads();
  if (t < 128) atomicAdd(&csum[b * 128 + t], cparts[0][t] + cparts[1][t]);
  {
    const int jr = t >> 1;
    const int ih = (t & 1) * 64;
    u16* dst = EunT + (size_t)b * 131072 + (size_t)jr * 1024 + m0 + ih;
#pragma unroll
    for (int s = 0; s < 8; ++s)
      *(short8*)(dst + s * 8) = *(const short8*)&Lt[jr][ih + s * 8];
  }
#pragma unroll
  for (int i = 0; i < 4; ++i)
#pragma unroll
    for (int g = 0; g < 4; ++g) {
      const int rl = wr * 64 + i * 16 + hi * 4 + g;
      const float M = fmaxf(rmaxs[0][rl], rmaxs[1][rl]);
      float s = 0.f;
#pragma unroll
      for (int j = 0; j < 4; ++j) {
        const float p = __expf(acc[i][j][g] - M);
        acc[i][j][g] = p;
        s += p;
      }
#pragma unroll
      for (int o = 8; o; o >>= 1) s += __shfl_xor(s, o);
      rtmp[i][g] = s;
    }
  if (fro == 0)
#pragma unroll
    for (int i = 0; i < 4; ++i)
#pragma unroll
      for (int g = 0; g < 4; ++g)
        rsums[wc][wr * 64 + i * 16 + hi * 4 + g] = rtmp[i][g];
  __syncthreads();
#pragma unroll
  for (int i = 0; i < 4; ++i)
#pragma unroll
    for (int g = 0; g < 4; ++g) {
      const int rl = wr * 64 + i * 16 + hi * 4 + g;
      const float inv = 1.f / (rsums[0][rl] + rsums[1][rl]);
#pragma unroll
      for (int j = 0; j < 4; ++j)
        Sbar[((size_t)b * 1024 + m0 + rl) * 128 + wc * 64 + j * 16 + fro] =
            f2bf(acc[i][j][g] * inv);
    }
}

// ---- prep: C fp32 -> Ct bf16 (ld 512), Corig bf16, cbias atomic ------------
__global__ __launch_bounds__(256) void prep_C(const float* __restrict__ C,
                                              const float* __restrict__ W0,
                                              u16* __restrict__ Ct,
                                              u16* __restrict__ Corig,
                                              float* __restrict__ cb) {
  __shared__ float L[64][65];
  __shared__ float P[4][64];
  const int b = blockIdx.z;
  const int d0 = blockIdx.y * 64;
  const int i0 = blockIdx.x * 64;
  const int t = threadIdx.x;
  const int cx = t & 63;
  const int rb = t >> 6;
  const float* Cb = C + ((size_t)b * 512 + d0) * 1024 + i0;
  float part = 0.f;
#pragma unroll
  for (int rr = 0; rr < 16; ++rr) {
    const int r = rb * 16 + rr;
    const float v = Cb[(size_t)r * 1024 + cx];
    L[r][cx] = v;
    part = fmaf(v, W0[d0 + r], part);
    Corig[((size_t)b * 512 + d0 + r) * 1024 + i0 + cx] = f2bf(v);
  }
  P[rb][cx] = part;
  __syncthreads();
#pragma unroll
  for (int rr = 0; rr < 16; ++rr) {
    const int il = rb * 16 + rr;
    Ct[((size_t)b * 1024 + i0 + il) * 512 + d0 + cx] = f2bf(L[cx][il]);
  }
  if (rb == 0)
    atomicAdd(&cb[b * 1024 + i0 + cx], P[0][cx] + P[1][cx] + P[2][cx] + P[3][cx]);
}

// ---- prep: Q -> Qmb = (Q_t * w_m) bf16, Qorig bf16, qbias atomic -----------
__global__ __launch_bounds__(256) void prep_Q(const float* __restrict__ Q,
                                              const float* __restrict__ W0,
                                              u16* __restrict__ Qmb,
                                              u16* __restrict__ Qorig,
                                              float* __restrict__ qb) {
  __shared__ float L[64][65];
  __shared__ float P[4][64];
  const int b = blockIdx.z;
  const int d0 = blockIdx.y * 64;
  const int j0 = blockIdx.x * 64;
  const int t = threadIdx.x;
  const int cx = t & 63;
  const int rb = t >> 6;
  const float* Qb = Q + ((size_t)b * 512 + d0) * 128 + j0;
  float part = 0.f;
#pragma unroll
  for (int rr = 0; rr < 16; ++rr) {
    const int r = rb * 16 + rr;
    const float v = Qb[(size_t)r * 128 + cx];
    L[r][cx] = v;
    part = fmaf(v, W0[512 + d0 + r], part);
    Qorig[((size_t)b * 512 + d0 + r) * 128 + j0 + cx] = f2bf(v);
  }
  P[rb][cx] = part;
  __syncthreads();
  const float wm = W0[1024 + d0 + cx];
#pragma unroll
  for (int rr = 0; rr < 16; ++rr) {
    const int jl = rb * 16 + rr;
    Qmb[((size_t)b * 128 + j0 + jl) * 512 + d0 + cx] = f2bf(L[cx][jl] * wm);
  }
  if (rb == 0)
    atomicAdd(&qb[b * 128 + j0 + cx], P[0][cx] + P[1][cx] + P[2][cx] + P[3][cx]);
}

// ---- Wr fp32 -> bf16 -------------------------------------------------------
__global__ __launch_bounds__(256) void cvt_wr(const float* __restrict__ Wr,
                                              u16* __restrict__ Wrb) {
  const int idx = blockIdx.x * 256 + threadIdx.x;
  const float4 v = ((const float4*)Wr)[idx];
  short4v o;
  o[0] = (short)f2bf(v.x);
  o[1] = (short)f2bf(v.y);
  o[2] = (short)f2bf(v.z);
  o[3] = (short)f2bf(v.w);
  *(short4v*)&Wrb[(size_t)idx * 4] = o;
}

extern "C" void kernel_launch(void* const* d_in, const int* in_sizes, int n_in,
                              void* d_out, int out_size, void* d_ws, size_t ws_size,
                              hipStream_t stream) {
  (void)in_sizes; (void)n_in; (void)out_size;
  const float* C = (const float*)d_in[0];
  const float* Q = (const float*)d_in[1];
  const float* cm = (const float*)d_in[2];
  const float* qm = (const float*)d_in[3];
  const float* W0 = (const float*)d_in[4];
  const float* Wr = (const float*)d_in[5];
  float* out = (float*)d_out;

  if (ws_size < 195362816ull) return;  // ~187 MiB scratch

  char* p = (char*)d_ws;
  u16* Ct    = (u16*)(p);                    // (B,1024,512) bf16
  u16* Corig = (u16*)(p + 67108864ull);      // (B,512,1024) bf16
  u16* Qmb   = (u16*)(p + 134217728ull);     // (B,128,512)  bf16
  u16* Qorig = (u16*)(p + 142606336ull);     // (B,512,128)  bf16
  u16* EunT  = (u16*)(p + 150994944ull);     // (B,128,1024) bf16
  u16* Sbar  = (u16*)(p + 167772160ull);     // (B,1024,128) bf16
  u16* Tt    = (u16*)(p + 184549376ull);     // (B,512,128)  bf16
  u16* Wrb   = (u16*)(p + 192937984ull);     // (512,2048)   bf16
  float* cb  = (float*)(p + 195035136ull);   // (B,1024)
  float* qb  = (float*)(p + 195297280ull);   // (B,128)
  float* csum= (float*)(p + 195330048ull);   // (B,128)

  (void)hipFuncSetAttribute((const void*)gemm_f,
                            hipFuncAttributeMaxDynamicSharedMemorySize, 163840);
  (void)hipMemsetAsync(cb, 0, 327680, stream);  // cb + qb + csum contiguous

  cvt_wr<<<dim3(1024), dim3(256), 0, stream>>>(Wr, Wrb);
  prep_C<<<dim3(16, 8, 64), dim3(256), 0, stream>>>(C, W0, Ct, Corig, cb);
  prep_Q<<<dim3(2, 8, 64), dim3(256), 0, stream>>>(Q, W0, Qmb, Qorig, qb);

  // S-GEMM + fused row softmax + transposed unnormalized col-exp
  gemm_s<<<dim3(8, 1, 64), dim3(256), 0, stream>>>(Ct, Qmb, cb, qb, cm, qm,
                                                   Sbar, EunT, csum);

  // T^T scaled: Tt[b][d][j] = (EunT @ Corig^T)[j][d] / csum[b][j]
  gemm_t<<<dim3(1, 4, 64), dim3(256), 0, stream>>>(EunT, Corig, csum, Tt);

  // Fused: A/Bm GEMMs + products + final projection -> out
  gemm_f<<<dim3(8, 64), dim3(512), 163840, stream>>>(Sbar, Qorig, Tt, Ct, Wrb,
                                                     out);
}

// Round 10
// 369.261 us; speedup vs baseline: 1.4797x; 1.4797x over previous
//
#include <hip/hip_runtime.h>
#include <hip/hip_bf16.h>

typedef unsigned short u16;
typedef __attribute__((ext_vector_type(8))) short short8;
typedef __attribute__((ext_vector_type(4))) short short4v;
typedef __attribute__((ext_vector_type(4))) float f32x4;
typedef __attribute__((ext_vector_type(16))) float f32x16;

#define NEGV -1000000000000000.0f
#define SBAR() asm volatile("s_barrier" ::: "memory")

__device__ __forceinline__ u16 f2bf(float f) {
  unsigned u = __float_as_uint(f);
  unsigned r = (u + 0x7FFFu + ((u >> 16) & 1u)) >> 16;
  return (u16)r;
}
__device__ __forceinline__ float bf2f(u16 s) {
  return __uint_as_float(((unsigned)s) << 16);
}
__device__ __forceinline__ void lds16(const void* g, void* l) {
  __builtin_amdgcn_global_load_lds((const __attribute__((address_space(1))) void*)g,
                                   (__attribute__((address_space(3))) void*)l,
                                   16, 0, 0);
}

// ============ 256x256 GEMM, 16 waves, 32x32x16 MFMA: out = Wrb @ Oflat^T ====
// r8 schedule (A dbuf 2x32K + B 3-buf; stage A(t+1)@p0, B(t+2)@p1; vmcnt(2))
// with 32x32 fragments: 16 MFMA/K-tile/wave at the higher 32x32 rate.
__global__ __launch_bounds__(1024) void gemm8c(const u16* __restrict__ A,
                                               const u16* __restrict__ B,
                                               float* __restrict__ out) {
  extern __shared__ u16 lds[];
  const int bid = blockIdx.x;
  const int wg = (bid & 7) * 64 + (bid >> 3);  // m-pair shares B-tile on one XCD
  const int m0 = (wg & 1) * 256;
  const int n0 = (wg >> 1) * 256;
  const int tid = threadIdx.x;
  const int lane = tid & 63;
  const int w = tid >> 6;   // 0..15
  const int wr = w >> 2;    // 64-row band
  const int wc = w & 3;     // 64-col band
  const int l31 = lane & 31;
  const int lhi = lane >> 5;
  const int kx = lane & 7;
  const int sr = lane >> 3;
  const int sgc = ((lane & 7) ^ sr) << 3;  // pre-swizzled source col (elems)

  const u16* Ag = A + (size_t)m0 * 2048;
  const u16* Bg = B + (size_t)n0 * 2048;
  const int rA = wr * 64 + l31;
  const int rB = wc * 64 + l31;

  f32x16 acc[2][2] = {};

#define STG(gp, lp) \
  lds16((gp) + (size_t)(w * 8 + sr) * 2048 + sgc, (u16*)(lp) + w * 512)
#define RDF(base, row, k16) \
  (*(const short8*)&(base)[(size_t)(row) * 64 + (((k16) ^ kx) << 3)])

  // prologue: A0, B0, B1
  STG(Ag, lds);
  STG(Ag + 262144, lds + 8192);
  STG(Bg, lds + 32768);
  STG(Bg + 262144, lds + 32768 + 8192);
  STG(Bg + 64, lds + 49152);
  STG(Bg + 262144 + 64, lds + 49152 + 8192);
  asm volatile("s_waitcnt vmcnt(2)" ::: "memory");  // A0,B0 done; B1 in flight
  SBAR();

  const u16* Ac = lds;
  u16* An = lds + 16384;
  const u16* Bc = lds + 32768;   // B(t)
  const u16* Bn = lds + 49152;   // B(t+1)
  u16* Bs2 = lds + 65536;        // stage target B(t+2)

  for (int t = 0; t < 32; ++t) {
    const int kkA = (t < 31 ? t + 1 : 31) * 64;
    const int kkB = (t < 30 ? t + 2 : 31) * 64;
    short8 af[2][2], bf[2][2];  // [ks][frag]

    // ---- phase 0 (ks=0,1): 8 ds_read; stage A(t+1); 8 MFMA(32x32)
#pragma unroll
    for (int ks = 0; ks < 2; ++ks)
#pragma unroll
      for (int f = 0; f < 2; ++f) {
        af[ks][f] = RDF(Ac, rA + f * 32, ks * 2 + lhi);
        bf[ks][f] = RDF(Bc, rB + f * 32, ks * 2 + lhi);
      }
    STG(Ag + kkA, An);
    STG(Ag + 262144 + kkA, An + 8192);
    SBAR();
    __builtin_amdgcn_s_setprio(1);
#pragma unroll
    for (int ks = 0; ks < 2; ++ks)
#pragma unroll
      for (int i = 0; i < 2; ++i)
#pragma unroll
        for (int j = 0; j < 2; ++j)
          acc[i][j] = __builtin_amdgcn_mfma_f32_32x32x16_bf16(
              af[ks][i], bf[ks][j], acc[i][j], 0, 0, 0);
    __builtin_amdgcn_s_setprio(0);
    SBAR();

    // ---- phase 1 (ks=2,3): 8 ds_read; stage B(t+2); vmcnt(2); 8 MFMA
#pragma unroll
    for (int ks = 0; ks < 2; ++ks)
#pragma unroll
      for (int f = 0; f < 2; ++f) {
        af[ks][f] = RDF(Ac, rA + f * 32, 4 + ks * 2 + lhi);
        bf[ks][f] = RDF(Bc, rB + f * 32, 4 + ks * 2 + lhi);
      }
    STG(Bg + kkB, Bs2);
    STG(Bg + 262144 + kkB, Bs2 + 8192);
    asm volatile("s_waitcnt vmcnt(2)" ::: "memory");  // drain B(t+1), A(t+1)
    SBAR();
    __builtin_amdgcn_s_setprio(1);
#pragma unroll
    for (int ks = 0; ks < 2; ++ks)
#pragma unroll
      for (int i = 0; i < 2; ++i)
#pragma unroll
        for (int j = 0; j < 2; ++j)
          acc[i][j] = __builtin_amdgcn_mfma_f32_32x32x16_bf16(
              af[ks][i], bf[ks][j], acc[i][j], 0, 0, 0);
    __builtin_amdgcn_s_setprio(0);
    SBAR();

    // rotate buffers
    u16* tA = An; An = (u16*)Ac; Ac = tA;
    u16* tB = (u16*)Bc; Bc = Bn; Bn = Bs2; Bs2 = tB;
  }
  asm volatile("s_waitcnt vmcnt(0)" ::: "memory");

  // ---- epilogue: C/D map col=lane&31, row=(reg&3)+8*(reg>>2)+4*(lane>>5)
  const int crow = m0 + wr * 64 + lhi * 4;
#pragma unroll
  for (int i = 0; i < 2; ++i)
#pragma unroll
    for (int j = 0; j < 2; ++j) {
      const int n = n0 + wc * 64 + j * 32 + l31;
      float* op = out + (size_t)(n >> 10) * 524288 + (n & 1023);
#pragma unroll
      for (int reg = 0; reg < 16; ++reg) {
        const int o = crow + i * 32 + (reg & 3) + 8 * (reg >> 2);
        op[(size_t)o * 1024] = acc[i][j][reg];
      }
    }
#undef STG
#undef RDF
}

// ============ T-GEMM: C_un = EunT(128x1024) @ Corig(512x1024)^T, then
// Tt[b][d][j] = C_un[j][d] / csum[b][j]  (transposed scaled store) ===========
__global__ __launch_bounds__(256) void gemm_t(const u16* __restrict__ A,
                                              const u16* __restrict__ B,
                                              const float* __restrict__ csum,
                                              u16* __restrict__ Tt) {
  __shared__ u16 As[128 * 64];
  __shared__ u16 Bs[128 * 64];
  const int b = blockIdx.z;
  const int n0 = blockIdx.y * 128;
  const u16* Ab = A + (size_t)b * 131072;
  const u16* Bb = B + (size_t)b * 524288;
  const int t = threadIdx.x;
  const int lane = t & 63;
  const int w = t >> 6;
  const int wr = w >> 1, wc = w & 1;
  const int srow = lane >> 3;
  const int scol = (lane & 7) * 8;

  f32x4 acc[4][4] = {};

  for (int k0 = 0; k0 < 1024; k0 += 64) {
    __syncthreads();
#pragma unroll
    for (int qq = 0; qq < 4; ++qq) {
      const int q = w * 4 + qq;
      const int r = q * 8 + srow;
      lds16(Ab + (size_t)r * 1024 + k0 + scol, &As[q * 512]);
      lds16(Bb + (size_t)(n0 + r) * 1024 + k0 + scol, &Bs[q * 512]);
    }
    __syncthreads();
#pragma unroll
    for (int ks = 0; ks < 2; ++ks) {
      short8 af[4], bg[4];
      const int fro = lane & 15;
      const int k8 = ks * 32 + (lane >> 4) * 8;
#pragma unroll
      for (int i = 0; i < 4; ++i)
        af[i] = *(const short8*)&As[(wr * 64 + i * 16 + fro) * 64 + k8];
#pragma unroll
      for (int i = 0; i < 4; ++i)
        bg[i] = *(const short8*)&Bs[(wc * 64 + i * 16 + fro) * 64 + k8];
#pragma unroll
      for (int i = 0; i < 4; ++i)
#pragma unroll
        for (int j = 0; j < 4; ++j)
          acc[i][j] =
              __builtin_amdgcn_mfma_f32_16x16x32_bf16(af[i], bg[j], acc[i][j], 0, 0, 0);
    }
  }

  const int col = lane & 15;
  const int r4 = (lane >> 4) * 4;
#pragma unroll
  for (int i = 0; i < 4; ++i)
#pragma unroll
    for (int g = 0; g < 4; ++g) {
      const int rr = wr * 64 + i * 16 + r4 + g;  // j index
      const float inv = 1.f / csum[b * 128 + rr];
#pragma unroll
      for (int j = 0; j < 4; ++j) {
        const int cc = n0 + wc * 64 + j * 16 + col;  // d index
        Tt[(size_t)b * 65536 + (size_t)cc * 128 + rr] = f2bf(acc[i][j][g] * inv);
      }
    }
}

// ============ S-GEMM + fused dual softmax + transposed-Eun epilogue =========
__global__ __launch_bounds__(256) void gemm_s(
    const u16* __restrict__ A, const u16* __restrict__ Bq,
    const float* __restrict__ cb, const float* __restrict__ qb,
    const float* __restrict__ cmask, const float* __restrict__ qmask,
    u16* __restrict__ Sbar, u16* __restrict__ EunT, float* __restrict__ csum) {
  __shared__ u16 As[128 * 64];
  __shared__ u16 Bs[128 * 64];
  __shared__ u16 Lt[128][136];
  __shared__ float rmaxs[2][128];
  __shared__ float rsums[2][128];
  __shared__ float cparts[2][128];
  const int b = blockIdx.z;
  const int m0 = blockIdx.x * 128;
  const u16* Ab = A + (size_t)b * 2097152;
  const u16* Bb = Bq + (size_t)b * 65536;
  const int t = threadIdx.x;
  const int lane = t & 63;
  const int w = t >> 6;
  const int wr = w >> 1, wc = w & 1;
  const int srow = lane >> 3;
  const int scol = (lane & 7) * 8;

  f32x4 acc[4][4] = {};

  for (int k0 = 0; k0 < 512; k0 += 64) {
    __syncthreads();
#pragma unroll
    for (int qq = 0; qq < 4; ++qq) {
      const int q = w * 4 + qq;
      const int r = q * 8 + srow;
      lds16(Ab + (size_t)(m0 + r) * 2048 + k0 + scol, &As[q * 512]);
      lds16(Bb + (size_t)r * 512 + k0 + scol, &Bs[q * 512]);
    }
    __syncthreads();
#pragma unroll
    for (int ks = 0; ks < 2; ++ks) {
      short8 af[4], bg[4];
      const int fro = lane & 15;
      const int k8 = ks * 32 + (lane >> 4) * 8;
#pragma unroll
      for (int i = 0; i < 4; ++i)
        af[i] = *(const short8*)&As[(wr * 64 + i * 16 + fro) * 64 + k8];
#pragma unroll
      for (int i = 0; i < 4; ++i)
        bg[i] = *(const short8*)&Bs[(wc * 64 + i * 16 + fro) * 64 + k8];
#pragma unroll
      for (int i = 0; i < 4; ++i)
#pragma unroll
        for (int j = 0; j < 4; ++j)
          acc[i][j] =
              __builtin_amdgcn_mfma_f32_16x16x32_bf16(af[i], bg[j], acc[i][j], 0, 0, 0);
    }
  }

  const int fro = lane & 15;
  const int hi = lane >> 4;
  float qv[4], qbv[4];
#pragma unroll
  for (int j = 0; j < 4; ++j) {
    const int cc = wc * 64 + j * 16 + fro;
    qv[j] = qmask[b * 128 + cc];
    qbv[j] = qb[b * 128 + cc];
  }
  float colp[4] = {0.f, 0.f, 0.f, 0.f};
#pragma unroll
  for (int i = 0; i < 4; ++i)
#pragma unroll
    for (int g = 0; g < 4; ++g) {
      const int rl = wr * 64 + i * 16 + hi * 4 + g;
      const float rb = cb[b * 1024 + m0 + rl];
      const float cv = cmask[b * 1024 + m0 + rl];
      const float coff = NEGV * (1.f - cv);
#pragma unroll
      for (int j = 0; j < 4; ++j) {
        const float v = acc[i][j][g] + rb + qbv[j];
        acc[i][j][g] = v;
        const float e = __expf(v * cv + coff);
        Lt[wc * 64 + j * 16 + fro][rl] = f2bf(e);
        colp[j] += e;
      }
    }
#pragma unroll
  for (int j = 0; j < 4; ++j) {
    colp[j] += __shfl_xor(colp[j], 16);
    colp[j] += __shfl_xor(colp[j], 32);
  }
  if (hi == 0)
#pragma unroll
    for (int j = 0; j < 4; ++j) cparts[wr][wc * 64 + j * 16 + fro] = colp[j];
  float rtmp[4][4];
#pragma unroll
  for (int i = 0; i < 4; ++i)
#pragma unroll
    for (int g = 0; g < 4; ++g) {
      float m = -3.4e38f;
#pragma unroll
      for (int j = 0; j < 4; ++j) {
        const float xm = acc[i][j][g] * qv[j] + NEGV * (1.f - qv[j]);
        acc[i][j][g] = xm;
        m = fmaxf(m, xm);
      }
#pragma unroll
      for (int o = 8; o; o >>= 1) m = fmaxf(m, __shfl_xor(m, o));
      rtmp[i][g] = m;
    }
  if (fro == 0)
#pragma unroll
    for (int i = 0; i < 4; ++i)
#pragma unroll
      for (int g = 0; g < 4; ++g)
        rmaxs[wc][wr * 64 + i * 16 + hi * 4 + g] = rtmp[i][g];
  __syncthreads();
  if (t < 128) atomicAdd(&csum[b * 128 + t], cparts[0][t] + cparts[1][t]);
  {
    const int jr = t >> 1;
    const int ih = (t & 1) * 64;
    u16* dst = EunT + (size_t)b * 131072 + (size_t)jr * 1024 + m0 + ih;
#pragma unroll
    for (int s = 0; s < 8; ++s)
      *(short8*)(dst + s * 8) = *(const short8*)&Lt[jr][ih + s * 8];
  }
#pragma unroll
  for (int i = 0; i < 4; ++i)
#pragma unroll
    for (int g = 0; g < 4; ++g) {
      const int rl = wr * 64 + i * 16 + hi * 4 + g;
      const float M = fmaxf(rmaxs[0][rl], rmaxs[1][rl]);
      float s = 0.f;
#pragma unroll
      for (int j = 0; j < 4; ++j) {
        const float p = __expf(acc[i][j][g] - M);
        acc[i][j][g] = p;
        s += p;
      }
#pragma unroll
      for (int o = 8; o; o >>= 1) s += __shfl_xor(s, o);
      rtmp[i][g] = s;
    }
  if (fro == 0)
#pragma unroll
    for (int i = 0; i < 4; ++i)
#pragma unroll
      for (int g = 0; g < 4; ++g)
        rsums[wc][wr * 64 + i * 16 + hi * 4 + g] = rtmp[i][g];
  __syncthreads();
#pragma unroll
  for (int i = 0; i < 4; ++i)
#pragma unroll
    for (int g = 0; g < 4; ++g) {
      const int rl = wr * 64 + i * 16 + hi * 4 + g;
      const float inv = 1.f / (rsums[0][rl] + rsums[1][rl]);
#pragma unroll
      for (int j = 0; j < 4; ++j)
        Sbar[((size_t)b * 1024 + m0 + rl) * 128 + wc * 64 + j * 16 + fro] =
            f2bf(acc[i][j][g] * inv);
    }
}

// ============ A+Bm GEMM v2: grid (dcol, b), Qo/Tt LDS-resident across all
// 8 m-tiles; Sbar double-buffered prefetch; swizzled [128][128] tiles. ======
__global__ __launch_bounds__(512) void gemm_ab2(const u16* __restrict__ Sbar,
                                                const u16* __restrict__ Qo,
                                                const u16* __restrict__ Tt,
                                                u16* __restrict__ O) {
  extern __shared__ u16 sh[];
  u16* LQ = sh;             // 32KB Qo tile
  u16* LT = sh + 16384;     // 32KB Tt tile
  u16* Ls = sh + 65536;     // 32KB epilogue scratch
  const int dcol = blockIdx.x * 128;
  const int b = blockIdx.y;
  const int t = threadIdx.x;
  const int lane = t & 63;
  const int w = t >> 6;
  const int wr = w >> 2, wc = w & 3;
  const int fro = lane & 15, hi = lane >> 4;
  const int srow4 = t >> 4;   // 0..31
  const int sslot = t & 15;   // 16B slot

  const u16* Qg = Qo + (size_t)b * 65536 + (size_t)dcol * 128;
  const u16* Tg = Tt + (size_t)b * 65536 + (size_t)dcol * 128;
  const u16* Sg = Sbar + (size_t)b * 131072;

#define STG32(gp, lp)                                                         \
  {                                                                           \
    _Pragma("unroll") for (int ii = 0; ii < 4; ++ii) {                        \
      const int row_ = ii * 32 + srow4;                                       \
      lds16((gp) + (size_t)row_ * 128 + ((sslot ^ (row_ & 7)) << 3),          \
            (u16*)(lp) + ii * 4096 + t * 8);                                  \
    }                                                                         \
  }
#define RDS(base, row, kslot)                                                 \
  (*(const short8*)&(base)[(size_t)(row) * 128 + (((kslot) ^ ((row) & 7)) << 3)])

  STG32(Qg, LQ);
  STG32(Tg, LT);
  STG32(Sg, sh + 32768);
  asm volatile("s_waitcnt vmcnt(0)" ::: "memory");
  __syncthreads();

  for (int mm = 0; mm < 8; ++mm) {
    const u16* LSc = sh + 32768 + ((size_t)(mm & 1) << 14);
    u16* LSn = sh + 32768 + ((size_t)((mm + 1) & 1) << 14);
    if (mm < 7) STG32(Sg + (size_t)(mm + 1) * 16384, LSn);

    f32x4 aa[4][2] = {};
    f32x4 ab[4][2] = {};
#pragma unroll
    for (int ks = 0; ks < 4; ++ks) {
      short8 af[4], bq[2], bt[2];
#pragma unroll
      for (int i = 0; i < 4; ++i) {
        const int r = wr * 64 + i * 16 + fro;
        af[i] = RDS(LSc, r, ks * 4 + hi);
      }
#pragma unroll
      for (int j = 0; j < 2; ++j) {
        const int r = wc * 32 + j * 16 + fro;
        bq[j] = RDS(LQ, r, ks * 4 + hi);
        bt[j] = RDS(LT, r, ks * 4 + hi);
      }
#pragma unroll
      for (int i = 0; i < 4; ++i)
#pragma unroll
        for (int j = 0; j < 2; ++j) {
          aa[i][j] =
              __builtin_amdgcn_mfma_f32_16x16x32_bf16(af[i], bq[j], aa[i][j], 0, 0, 0);
          ab[i][j] =
              __builtin_amdgcn_mfma_f32_16x16x32_bf16(af[i], bt[j], ab[i][j], 0, 0, 0);
        }
    }

    const size_t obase = (size_t)b * 2097152 + (size_t)mm * 262144 + dcol;
    __syncthreads();  // drains prefetch too
#pragma unroll
    for (int i = 0; i < 4; ++i)
#pragma unroll
      for (int j = 0; j < 2; ++j)
#pragma unroll
        for (int g = 0; g < 4; ++g)
          Ls[(wr * 64 + i * 16 + hi * 4 + g) * 128 + wc * 32 + j * 16 + fro] =
              f2bf(aa[i][j][g]);
    __syncthreads();
    short8 c8[4];
#pragma unroll
    for (int it = 0; it < 4; ++it) {
      const int row = it * 32 + srow4;
      const short8 a8 = *(const short8*)&Ls[row * 128 + sslot * 8];
      c8[it] = *(const short8*)&O[obase + (size_t)row * 2048 + sslot * 8];
      short8 p2;
#pragma unroll
      for (int k = 0; k < 8; ++k)
        p2[k] = (short)f2bf(bf2f((u16)c8[it][k]) * bf2f((u16)a8[k]));
      *(short8*)&O[obase + (size_t)row * 2048 + sslot * 8 + 512] = a8;
      *(short8*)&O[obase + (size_t)row * 2048 + sslot * 8 + 1024] = p2;
    }
    __syncthreads();
#pragma unroll
    for (int i = 0; i < 4; ++i)
#pragma unroll
      for (int j = 0; j < 2; ++j)
#pragma unroll
        for (int g = 0; g < 4; ++g)
          Ls[(wr * 64 + i * 16 + hi * 4 + g) * 128 + wc * 32 + j * 16 + fro] =
              f2bf(ab[i][j][g]);
    __syncthreads();
#pragma unroll
    for (int it = 0; it < 4; ++it) {
      const int row = it * 32 + srow4;
      const short8 b8 = *(const short8*)&Ls[row * 128 + sslot * 8];
      short8 p3;
#pragma unroll
      for (int k = 0; k < 8; ++k)
        p3[k] = (short)f2bf(bf2f((u16)c8[it][k]) * bf2f((u16)b8[k]));
      *(short8*)&O[obase + (size_t)row * 2048 + sslot * 8 + 1536] = p3;
    }
    __syncthreads();
  }
#undef STG32
#undef RDS
}

// ---- prep: C fp32 -> O chunk0 = C_t bf16 (ld 2048), Corig bf16, cbias atomic
__global__ __launch_bounds__(256) void prep_C(const float* __restrict__ C,
                                              const float* __restrict__ W0,
                                              u16* __restrict__ O,
                                              u16* __restrict__ Corig,
                                              float* __restrict__ cb) {
  __shared__ float L[64][65];
  __shared__ float P[4][64];
  const int b = blockIdx.z;
  const int d0 = blockIdx.y * 64;
  const int i0 = blockIdx.x * 64;
  const int t = threadIdx.x;
  const int cx = t & 63;
  const int rb = t >> 6;
  const float* Cb = C + ((size_t)b * 512 + d0) * 1024 + i0;
  float part = 0.f;
#pragma unroll
  for (int rr = 0; rr < 16; ++rr) {
    const int r = rb * 16 + rr;
    const float v = Cb[(size_t)r * 1024 + cx];
    L[r][cx] = v;
    part = fmaf(v, W0[d0 + r], part);
    Corig[((size_t)b * 512 + d0 + r) * 1024 + i0 + cx] = f2bf(v);
  }
  P[rb][cx] = part;
  __syncthreads();
#pragma unroll
  for (int rr = 0; rr < 16; ++rr) {
    const int il = rb * 16 + rr;
    O[((size_t)b * 1024 + i0 + il) * 2048 + d0 + cx] = f2bf(L[cx][il]);
  }
  if (rb == 0)
    atomicAdd(&cb[b * 1024 + i0 + cx], P[0][cx] + P[1][cx] + P[2][cx] + P[3][cx]);
}

// ---- prep: Q -> Qmb = (Q_t * w_m) bf16, Qorig bf16, qbias atomic -----------
__global__ __launch_bounds__(256) void prep_Q(const float* __restrict__ Q,
                                              const float* __restrict__ W0,
                                              u16* __restrict__ Qmb,
                                              u16* __restrict__ Qorig,
                                              float* __restrict__ qb) {
  __shared__ float L[64][65];
  __shared__ float P[4][64];
  const int b = blockIdx.z;
  const int d0 = blockIdx.y * 64;
  const int j0 = blockIdx.x * 64;
  const int t = threadIdx.x;
  const int cx = t & 63;
  const int rb = t >> 6;
  const float* Qb = Q + ((size_t)b * 512 + d0) * 128 + j0;
  float part = 0.f;
#pragma unroll
  for (int rr = 0; rr < 16; ++rr) {
    const int r = rb * 16 + rr;
    const float v = Qb[(size_t)r * 128 + cx];
    L[r][cx] = v;
    part = fmaf(v, W0[512 + d0 + r], part);
    Qorig[((size_t)b * 512 + d0 + r) * 128 + j0 + cx] = f2bf(v);
  }
  P[rb][cx] = part;
  __syncthreads();
  const float wm = W0[1024 + d0 + cx];
#pragma unroll
  for (int rr = 0; rr < 16; ++rr) {
    const int jl = rb * 16 + rr;
    Qmb[((size_t)b * 128 + j0 + jl) * 512 + d0 + cx] = f2bf(L[cx][jl] * wm);
  }
  if (rb == 0)
    atomicAdd(&qb[b * 128 + j0 + cx], P[0][cx] + P[1][cx] + P[2][cx] + P[3][cx]);
}

// ---- Wr fp32 -> bf16 -------------------------------------------------------
__global__ __launch_bounds__(256) void cvt_wr(const float* __restrict__ Wr,
                                              u16* __restrict__ Wrb) {
  const int idx = blockIdx.x * 256 + threadIdx.x;
  const float4 v = ((const float4*)Wr)[idx];
  short4v o;
  o[0] = (short)f2bf(v.x);
  o[1] = (short)f2bf(v.y);
  o[2] = (short)f2bf(v.z);
  o[3] = (short)f2bf(v.w);
  *(short4v*)&Wrb[(size_t)idx * 4] = o;
}

extern "C" void kernel_launch(void* const* d_in, const int* in_sizes, int n_in,
                              void* d_out, int out_size, void* d_ws, size_t ws_size,
                              hipStream_t stream) {
  (void)in_sizes; (void)n_in; (void)out_size;
  const float* C = (const float*)d_in[0];
  const float* Q = (const float*)d_in[1];
  const float* cm = (const float*)d_in[2];
  const float* qm = (const float*)d_in[3];
  const float* W0 = (const float*)d_in[4];
  const float* Wr = (const float*)d_in[5];
  float* out = (float*)d_out;

  if (ws_size < 405078016ull) return;  // ~386 MiB scratch

  char* p = (char*)d_ws;
  u16* O     = (u16*)(p);                    // (B,1024,2048) bf16 [C_t|A|C*A|C*Bm]
  u16* Corig = (u16*)(p + 268435456ull);     // (B,512,1024) bf16
  u16* Qmb   = (u16*)(p + 335544320ull);     // (B,128,512)  bf16
  u16* Qorig = (u16*)(p + 343932928ull);     // (B,512,128)  bf16
  u16* EunT  = (u16*)(p + 360710144ull);     // (B,128,1024) bf16 unnorm col-exp^T
  u16* Sbar  = (u16*)(p + 377487360ull);     // (B,1024,128) bf16
  u16* Tt    = (u16*)(p + 394264576ull);     // (B,512,128)  bf16
  u16* Wrb   = (u16*)(p + 402653184ull);     // (512,2048)   bf16
  float* cb  = (float*)(p + 404750336ull);   // (B,1024)
  float* qb  = (float*)(p + 405012480ull);   // (B,128)
  float* csum= (float*)(p + 405045248ull);   // (B,128)

  (void)hipFuncSetAttribute((const void*)gemm8c,
                            hipFuncAttributeMaxDynamicSharedMemorySize, 163840);
  (void)hipFuncSetAttribute((const void*)gemm_ab2,
                            hipFuncAttributeMaxDynamicSharedMemorySize, 163840);
  (void)hipMemsetAsync(cb, 0, 327680, stream);  // cb + qb + csum contiguous

  cvt_wr<<<dim3(1024), dim3(256), 0, stream>>>(Wr, Wrb);
  prep_C<<<dim3(16, 8, 64), dim3(256), 0, stream>>>(C, W0, O, Corig, cb);
  prep_Q<<<dim3(2, 8, 64), dim3(256), 0, stream>>>(Q, W0, Qmb, Qorig, qb);

  // S-GEMM + fused row softmax + transposed unnormalized col-exp
  gemm_s<<<dim3(8, 1, 64), dim3(256), 0, stream>>>(O, Qmb, cb, qb, cm, qm,
                                                   Sbar, EunT, csum);

  // T^T scaled: Tt[b][d][j] = (EunT @ Corig^T)[j][d] / csum[b][j]
  gemm_t<<<dim3(1, 4, 64), dim3(256), 0, stream>>>(EunT, Corig, csum, Tt);

  // A & Bm: Qo/Tt LDS-resident, loop m-tiles, chunks 1,2,3 of O
  gemm_ab2<<<dim3(4, 64), dim3(512), 163840, stream>>>(Sbar, Qorig, Tt, O);

  // R = Wr @ out^T : flat M=512, N=65536, K=2048; 16-wave 256^2, 32x32 MFMA
  gemm8c<<<dim3(512), dim3(1024), 163840, stream>>>(Wrb, O, out);
}

// Round 11
// 350.969 us; speedup vs baseline: 1.5569x; 1.0521x over previous
//
#include <hip/hip_runtime.h>
#include <hip/hip_bf16.h>

typedef unsigned short u16;
typedef __attribute__((ext_vector_type(8))) short short8;
typedef __attribute__((ext_vector_type(4))) short short4v;
typedef __attribute__((ext_vector_type(4))) float f32x4;

#define NEGV -1000000000000000.0f
#define SBAR() asm volatile("s_barrier" ::: "memory")

__device__ __forceinline__ u16 f2bf(float f) {
  unsigned u = __float_as_uint(f);
  unsigned r = (u + 0x7FFFu + ((u >> 16) & 1u)) >> 16;
  return (u16)r;
}
__device__ __forceinline__ float bf2f(u16 s) {
  return __uint_as_float(((unsigned)s) << 16);
}
__device__ __forceinline__ void lds16(const void* g, void* l) {
  __builtin_amdgcn_global_load_lds((const __attribute__((address_space(1))) void*)g,
                                   (__attribute__((address_space(3))) void*)l,
                                   16, 0, 0);
}

// ============ 256x256 GEMM, 16 waves (4Mx4N, 64x64/wave): out = Wrb @ O^T ===
// (r8 verified, 148us.) LDS 160KB: A dbuf 2x32K + B 3-buf 3x32K.
// 2 phases/K-tile; stage A(t+1)@p0, B(t+2)@p1; uniform vmcnt(2)@p1.
__global__ __launch_bounds__(1024) void gemm8b(const u16* __restrict__ A,
                                               const u16* __restrict__ B,
                                               float* __restrict__ out) {
  extern __shared__ u16 lds[];
  const int bid = blockIdx.x;
  const int wg = (bid & 7) * 64 + (bid >> 3);  // m-pair shares B-tile on one XCD
  const int m0 = (wg & 1) * 256;
  const int n0 = (wg >> 1) * 256;
  const int tid = threadIdx.x;
  const int lane = tid & 63;
  const int w = tid >> 6;   // 0..15
  const int wr = w >> 2;    // 64-row band
  const int wc = w & 3;     // 64-col band
  const int fro = lane & 15;
  const int hi = lane >> 4;
  const int kx = fro & 7;
  const int sr = lane >> 3;
  const int sgc = ((lane & 7) ^ sr) << 3;  // pre-swizzled source col (elems)

  const u16* Ag = A + (size_t)m0 * 2048;
  const u16* Bg = B + (size_t)n0 * 2048;
  const int rA = wr * 64 + fro;
  const int rB = wc * 64 + fro;

  f32x4 acc[4][4] = {};

#define STG(gp, lp) \
  lds16((gp) + (size_t)(w * 8 + sr) * 2048 + sgc, (u16*)(lp) + w * 512)
#define RDF(base, row, k16) \
  (*(const short8*)&(base)[(size_t)(row) * 64 + (((k16) ^ kx) << 3)])

  // prologue: A0, B0, B1
  STG(Ag, lds);
  STG(Ag + 262144, lds + 8192);
  STG(Bg, lds + 32768);
  STG(Bg + 262144, lds + 32768 + 8192);
  STG(Bg + 64, lds + 49152);
  STG(Bg + 262144 + 64, lds + 57344);
  asm volatile("s_waitcnt vmcnt(2)" ::: "memory");  // A0,B0 done; B1 in flight
  SBAR();

  const u16* Ac = lds;
  u16* An = lds + 16384;
  const u16* Bc = lds + 32768;   // B(t)
  const u16* Bn = lds + 49152;   // B(t+1)
  u16* Bs2 = lds + 65536;        // stage target B(t+2)

  for (int t = 0; t < 32; ++t) {
    const int kkA = (t < 31 ? t + 1 : 31) * 64;
    const int kkB = (t < 30 ? t + 2 : 31) * 64;
    short8 af[4], bf[4];

    // ---- phase 0 (ks=0): 8 ds_read; stage A(t+1); 16 MFMA
#pragma unroll
    for (int i = 0; i < 4; ++i) af[i] = RDF(Ac, rA + i * 16, hi);
#pragma unroll
    for (int j = 0; j < 4; ++j) bf[j] = RDF(Bc, rB + j * 16, hi);
    STG(Ag + kkA, An);
    STG(Ag + 262144 + kkA, An + 8192);
    SBAR();
    __builtin_amdgcn_s_setprio(1);
#pragma unroll
    for (int i = 0; i < 4; ++i)
#pragma unroll
      for (int j = 0; j < 4; ++j)
        acc[i][j] =
            __builtin_amdgcn_mfma_f32_16x16x32_bf16(af[i], bf[j], acc[i][j], 0, 0, 0);
    __builtin_amdgcn_s_setprio(0);
    SBAR();

    // ---- phase 1 (ks=1): 8 ds_read; stage B(t+2); vmcnt(2); 16 MFMA
#pragma unroll
    for (int i = 0; i < 4; ++i) af[i] = RDF(Ac, rA + i * 16, 4 + hi);
#pragma unroll
    for (int j = 0; j < 4; ++j) bf[j] = RDF(Bc, rB + j * 16, 4 + hi);
    STG(Bg + kkB, Bs2);
    STG(Bg + 262144 + kkB, Bs2 + 8192);
    asm volatile("s_waitcnt vmcnt(2)" ::: "memory");  // drain B(t+1), A(t+1)
    SBAR();
    __builtin_amdgcn_s_setprio(1);
#pragma unroll
    for (int i = 0; i < 4; ++i)
#pragma unroll
      for (int j = 0; j < 4; ++j)
        acc[i][j] =
            __builtin_amdgcn_mfma_f32_16x16x32_bf16(af[i], bf[j], acc[i][j], 0, 0, 0);
    __builtin_amdgcn_s_setprio(0);
    SBAR();

    // rotate buffers
    u16* tA = An; An = (u16*)Ac; Ac = tA;
    u16* tB = (u16*)Bc; Bc = Bn; Bn = Bs2; Bs2 = tB;
  }
  asm volatile("s_waitcnt vmcnt(0)" ::: "memory");

  // ---- epilogue: out[b][r][c], n = n0 + wc*64 + j*16 + fro
  const int crow = m0 + wr * 64 + hi * 4;
#pragma unroll
  for (int i = 0; i < 4; ++i)
#pragma unroll
    for (int j = 0; j < 4; ++j) {
      const int n = n0 + wc * 64 + j * 16 + fro;
      float* op = out + (size_t)(n >> 10) * 524288 + (n & 1023);
#pragma unroll
      for (int g = 0; g < 4; ++g)
        op[(size_t)(crow + i * 16 + g) * 1024] = acc[i][j][g];
    }
#undef STG
#undef RDF
}

// ============ S-GEMM + fused dual softmax + transposed-Eun epilogue =========
__global__ __launch_bounds__(256) void gemm_s(
    const u16* __restrict__ A, const u16* __restrict__ Bq,
    const float* __restrict__ cb, const float* __restrict__ qb,
    const float* __restrict__ cmask, const float* __restrict__ qmask,
    u16* __restrict__ Sbar, u16* __restrict__ EunT, float* __restrict__ csum) {
  __shared__ u16 As[128 * 64];
  __shared__ u16 Bs[128 * 64];
  __shared__ u16 Lt[128][136];
  __shared__ float rmaxs[2][128];
  __shared__ float rsums[2][128];
  __shared__ float cparts[2][128];
  const int b = blockIdx.z;
  const int m0 = blockIdx.x * 128;
  const u16* Ab = A + (size_t)b * 2097152;
  const u16* Bb = Bq + (size_t)b * 65536;
  const int t = threadIdx.x;
  const int lane = t & 63;
  const int w = t >> 6;
  const int wr = w >> 1, wc = w & 1;
  const int srow = lane >> 3;
  const int scol = (lane & 7) * 8;

  f32x4 acc[4][4] = {};

  for (int k0 = 0; k0 < 512; k0 += 64) {
    __syncthreads();
#pragma unroll
    for (int qq = 0; qq < 4; ++qq) {
      const int q = w * 4 + qq;
      const int r = q * 8 + srow;
      lds16(Ab + (size_t)(m0 + r) * 2048 + k0 + scol, &As[q * 512]);
      lds16(Bb + (size_t)r * 512 + k0 + scol, &Bs[q * 512]);
    }
    __syncthreads();
#pragma unroll
    for (int ks = 0; ks < 2; ++ks) {
      short8 af[4], bg[4];
      const int fro = lane & 15;
      const int k8 = ks * 32 + (lane >> 4) * 8;
#pragma unroll
      for (int i = 0; i < 4; ++i)
        af[i] = *(const short8*)&As[(wr * 64 + i * 16 + fro) * 64 + k8];
#pragma unroll
      for (int i = 0; i < 4; ++i)
        bg[i] = *(const short8*)&Bs[(wc * 64 + i * 16 + fro) * 64 + k8];
#pragma unroll
      for (int i = 0; i < 4; ++i)
#pragma unroll
        for (int j = 0; j < 4; ++j)
          acc[i][j] =
              __builtin_amdgcn_mfma_f32_16x16x32_bf16(af[i], bg[j], acc[i][j], 0, 0, 0);
    }
  }

  const int fro = lane & 15;
  const int hi = lane >> 4;
  float qv[4], qbv[4];
#pragma unroll
  for (int j = 0; j < 4; ++j) {
    const int cc = wc * 64 + j * 16 + fro;
    qv[j] = qmask[b * 128 + cc];
    qbv[j] = qb[b * 128 + cc];
  }
  float colp[4] = {0.f, 0.f, 0.f, 0.f};
#pragma unroll
  for (int i = 0; i < 4; ++i)
#pragma unroll
    for (int g = 0; g < 4; ++g) {
      const int rl = wr * 64 + i * 16 + hi * 4 + g;
      const float rb = cb[b * 1024 + m0 + rl];
      const float cv = cmask[b * 1024 + m0 + rl];
      const float coff = NEGV * (1.f - cv);
#pragma unroll
      for (int j = 0; j < 4; ++j) {
        const float v = acc[i][j][g] + rb + qbv[j];
        acc[i][j][g] = v;
        const float e = __expf(v * cv + coff);
        Lt[wc * 64 + j * 16 + fro][rl] = f2bf(e);
        colp[j] += e;
      }
    }
#pragma unroll
  for (int j = 0; j < 4; ++j) {
    colp[j] += __shfl_xor(colp[j], 16);
    colp[j] += __shfl_xor(colp[j], 32);
  }
  if (hi == 0)
#pragma unroll
    for (int j = 0; j < 4; ++j) cparts[wr][wc * 64 + j * 16 + fro] = colp[j];
  float rtmp[4][4];
#pragma unroll
  for (int i = 0; i < 4; ++i)
#pragma unroll
    for (int g = 0; g < 4; ++g) {
      float m = -3.4e38f;
#pragma unroll
      for (int j = 0; j < 4; ++j) {
        const float xm = acc[i][j][g] * qv[j] + NEGV * (1.f - qv[j]);
        acc[i][j][g] = xm;
        m = fmaxf(m, xm);
      }
#pragma unroll
      for (int o = 8; o; o >>= 1) m = fmaxf(m, __shfl_xor(m, o));
      rtmp[i][g] = m;
    }
  if (fro == 0)
#pragma unroll
    for (int i = 0; i < 4; ++i)
#pragma unroll
      for (int g = 0; g < 4; ++g)
        rmaxs[wc][wr * 64 + i * 16 + hi * 4 + g] = rtmp[i][g];
  __syncthreads();
  if (t < 128) atomicAdd(&csum[b * 128 + t], cparts[0][t] + cparts[1][t]);
  {
    const int jr = t >> 1;
    const int ih = (t & 1) * 64;
    u16* dst = EunT + (size_t)b * 131072 + (size_t)jr * 1024 + m0 + ih;
#pragma unroll
    for (int s = 0; s < 8; ++s)
      *(short8*)(dst + s * 8) = *(const short8*)&Lt[jr][ih + s * 8];
  }
#pragma unroll
  for (int i = 0; i < 4; ++i)
#pragma unroll
    for (int g = 0; g < 4; ++g) {
      const int rl = wr * 64 + i * 16 + hi * 4 + g;
      const float M = fmaxf(rmaxs[0][rl], rmaxs[1][rl]);
      float s = 0.f;
#pragma unroll
      for (int j = 0; j < 4; ++j) {
        const float p = __expf(acc[i][j][g] - M);
        acc[i][j][g] = p;
        s += p;
      }
#pragma unroll
      for (int o = 8; o; o >>= 1) s += __shfl_xor(s, o);
      rtmp[i][g] = s;
    }
  if (fro == 0)
#pragma unroll
    for (int i = 0; i < 4; ++i)
#pragma unroll
      for (int g = 0; g < 4; ++g)
        rsums[wc][wr * 64 + i * 16 + hi * 4 + g] = rtmp[i][g];
  __syncthreads();
#pragma unroll
  for (int i = 0; i < 4; ++i)
#pragma unroll
    for (int g = 0; g < 4; ++g) {
      const int rl = wr * 64 + i * 16 + hi * 4 + g;
      const float inv = 1.f / (rsums[0][rl] + rsums[1][rl]);
#pragma unroll
      for (int j = 0; j < 4; ++j)
        Sbar[((size_t)b * 1024 + m0 + rl) * 128 + wc * 64 + j * 16 + fro] =
            f2bf(acc[i][j][g] * inv);
    }
}

// ============ merged T-GEMM + A/Bm GEMM: grid (dcol, b), 512 thr, 160KB =====
// Phase T: T_tile[128d][128j] = (EunT @ Corig[dcol]^T)/csum -> LT (swizzled,
// never touches global). Phase AB: r8's gemm_ab2 flow (Qo/LT LDS-resident,
// Sbar dbuf prefetch, chunks 1,2,3 of O with fused C_t products).
__global__ __launch_bounds__(512) void gemm_tab(
    const u16* __restrict__ EunT, const u16* __restrict__ Corig,
    const float* __restrict__ csum, const u16* __restrict__ Sbar,
    const u16* __restrict__ Qo, u16* __restrict__ O) {
  extern __shared__ u16 sh[];
  u16* LQ = sh;             // 32KB Qo tile [128d][128j]
  u16* LT = sh + 16384;     // 32KB T tile  [128d][128j]
  u16* TA = sh + 32768;     // 16KB EunT K-tile [128j][64i]  (reused by LS dbuf)
  u16* TB = sh + 40960;     // 16KB Corig K-tile [128d][64i]
  u16* Ls = sh + 65536;     // 32KB epilogue scratch
  const int dcol = blockIdx.x * 128;
  const int b = blockIdx.y;
  const int t = threadIdx.x;
  const int lane = t & 63;
  const int w = t >> 6;
  const int wr = w >> 2, wc = w & 3;
  const int fro = lane & 15, hi = lane >> 4;
  const int srow4 = t >> 4;   // 0..31
  const int sslot = t & 15;   // 16B slot

#define STG32(gp, lp)                                                         \
  {                                                                           \
    _Pragma("unroll") for (int ii = 0; ii < 4; ++ii) {                        \
      const int row_ = ii * 32 + srow4;                                       \
      lds16((gp) + (size_t)row_ * 128 + ((sslot ^ (row_ & 7)) << 3),          \
            (u16*)(lp) + ii * 4096 + t * 8);                                  \
    }                                                                         \
  }
#define RDS(base, row, kslot)                                                 \
  (*(const short8*)&(base)[(size_t)(row) * 128 + (((kslot) ^ ((row) & 7)) << 3)])
// stage a 128x64 bf16 K-tile (linear layout [row][64]), 2 gloads/thread
#define TSTG(gp, lp)                                                          \
  {                                                                           \
    _Pragma("unroll") for (int q = 0; q < 2; ++q) {                           \
      const int row_ = q * 64 + (t >> 3);                                     \
      lds16((gp) + (size_t)row_ * 1024 + ((t & 7) << 3),                      \
            (u16*)(lp) + q * 4096 + t * 8);                                   \
    }                                                                         \
  }

  // ---- issue LQ stage early; completes under phase T's first sync
  STG32(Qo + (size_t)b * 65536 + (size_t)dcol * 128, LQ);

  // ================= phase T =================
  {
    const u16* Ag = EunT + (size_t)b * 131072;                       // [128j][1024i]
    const u16* Bg = Corig + (size_t)b * 524288 + (size_t)dcol * 1024;// [128d][1024i]
    f32x4 acc[4][2] = {};
    for (int k0 = 0; k0 < 1024; k0 += 64) {
      __syncthreads();
      TSTG(Ag + k0, TA);
      TSTG(Bg + k0, TB);
      __syncthreads();
#pragma unroll
      for (int ks = 0; ks < 2; ++ks) {
        short8 af[4], bg[2];
        const int k8 = ks * 32 + hi * 8;
#pragma unroll
        for (int i = 0; i < 4; ++i)
          af[i] = *(const short8*)&TA[(wr * 64 + i * 16 + fro) * 64 + k8];
#pragma unroll
        for (int jf = 0; jf < 2; ++jf)
          bg[jf] = *(const short8*)&TB[(wc * 32 + jf * 16 + fro) * 64 + k8];
#pragma unroll
        for (int i = 0; i < 4; ++i)
#pragma unroll
          for (int jf = 0; jf < 2; ++jf)
            acc[i][jf] = __builtin_amdgcn_mfma_f32_16x16x32_bf16(
                af[i], bg[jf], acc[i][jf], 0, 0, 0);
      }
    }
    // T epilogue: scale by 1/csum[j], write LT in ab-swizzled layout
    const int col = lane & 15;
    const int r4 = hi * 4;
#pragma unroll
    for (int i = 0; i < 4; ++i)
#pragma unroll
      for (int g = 0; g < 4; ++g) {
        const int j = wr * 64 + i * 16 + r4 + g;
        const float inv = 1.f / csum[b * 128 + j];
#pragma unroll
        for (int jf = 0; jf < 2; ++jf) {
          const int d = wc * 32 + jf * 16 + col;
          LT[d * 128 + (((j >> 3) ^ (d & 7)) << 3) + (j & 7)] =
              f2bf(acc[i][jf][g] * inv);
        }
      }
  }
  __syncthreads();  // LT visible; TA/TB free for LS dbuf reuse

  // ================= phase AB (r8 gemm_ab2 flow) =================
  const u16* Sg = Sbar + (size_t)b * 131072;
  STG32(Sg, sh + 32768);
  asm volatile("s_waitcnt vmcnt(0)" ::: "memory");
  __syncthreads();

  for (int mm = 0; mm < 8; ++mm) {
    const u16* LSc = sh + 32768 + ((size_t)(mm & 1) << 14);
    u16* LSn = sh + 32768 + ((size_t)((mm + 1) & 1) << 14);
    if (mm < 7) STG32(Sg + (size_t)(mm + 1) * 16384, LSn);

    f32x4 aa[4][2] = {};
    f32x4 ab[4][2] = {};
#pragma unroll
    for (int ks = 0; ks < 4; ++ks) {
      short8 af[4], bq[2], bt[2];
#pragma unroll
      for (int i = 0; i < 4; ++i) {
        const int r = wr * 64 + i * 16 + fro;
        af[i] = RDS(LSc, r, ks * 4 + hi);
      }
#pragma unroll
      for (int j = 0; j < 2; ++j) {
        const int r = wc * 32 + j * 16 + fro;
        bq[j] = RDS(LQ, r, ks * 4 + hi);
        bt[j] = RDS(LT, r, ks * 4 + hi);
      }
#pragma unroll
      for (int i = 0; i < 4; ++i)
#pragma unroll
        for (int j = 0; j < 2; ++j) {
          aa[i][j] =
              __builtin_amdgcn_mfma_f32_16x16x32_bf16(af[i], bq[j], aa[i][j], 0, 0, 0);
          ab[i][j] =
              __builtin_amdgcn_mfma_f32_16x16x32_bf16(af[i], bt[j], ab[i][j], 0, 0, 0);
        }
    }

    const size_t obase = (size_t)b * 2097152 + (size_t)mm * 262144 + dcol;
    __syncthreads();  // drains prefetch too
#pragma unroll
    for (int i = 0; i < 4; ++i)
#pragma unroll
      for (int j = 0; j < 2; ++j)
#pragma unroll
        for (int g = 0; g < 4; ++g)
          Ls[(wr * 64 + i * 16 + hi * 4 + g) * 128 + wc * 32 + j * 16 + fro] =
              f2bf(aa[i][j][g]);
    __syncthreads();
    short8 c8[4];
#pragma unroll
    for (int it = 0; it < 4; ++it) {
      const int row = it * 32 + srow4;
      const short8 a8 = *(const short8*)&Ls[row * 128 + sslot * 8];
      c8[it] = *(const short8*)&O[obase + (size_t)row * 2048 + sslot * 8];
      short8 p2;
#pragma unroll
      for (int k = 0; k < 8; ++k)
        p2[k] = (short)f2bf(bf2f((u16)c8[it][k]) * bf2f((u16)a8[k]));
      *(short8*)&O[obase + (size_t)row * 2048 + sslot * 8 + 512] = a8;
      *(short8*)&O[obase + (size_t)row * 2048 + sslot * 8 + 1024] = p2;
    }
    __syncthreads();
#pragma unroll
    for (int i = 0; i < 4; ++i)
#pragma unroll
      for (int j = 0; j < 2; ++j)
#pragma unroll
        for (int g = 0; g < 4; ++g)
          Ls[(wr * 64 + i * 16 + hi * 4 + g) * 128 + wc * 32 + j * 16 + fro] =
              f2bf(ab[i][j][g]);
    __syncthreads();
#pragma unroll
    for (int it = 0; it < 4; ++it) {
      const int row = it * 32 + srow4;
      const short8 b8 = *(const short8*)&Ls[row * 128 + sslot * 8];
      short8 p3;
#pragma unroll
      for (int k = 0; k < 8; ++k)
        p3[k] = (short)f2bf(bf2f((u16)c8[it][k]) * bf2f((u16)b8[k]));
      *(short8*)&O[obase + (size_t)row * 2048 + sslot * 8 + 1536] = p3;
    }
    __syncthreads();
  }
#undef STG32
#undef RDS
#undef TSTG
}

// ---- prep: C fp32 -> O chunk0 = C_t bf16 (ld 2048), Corig bf16, cbias atomic
__global__ __launch_bounds__(256) void prep_C(const float* __restrict__ C,
                                              const float* __restrict__ W0,
                                              u16* __restrict__ O,
                                              u16* __restrict__ Corig,
                                              float* __restrict__ cb) {
  __shared__ float L[64][65];
  __shared__ float P[4][64];
  const int b = blockIdx.z;
  const int d0 = blockIdx.y * 64;
  const int i0 = blockIdx.x * 64;
  const int t = threadIdx.x;
  const int cx = t & 63;
  const int rb = t >> 6;
  const float* Cb = C + ((size_t)b * 512 + d0) * 1024 + i0;
  float part = 0.f;
#pragma unroll
  for (int rr = 0; rr < 16; ++rr) {
    const int r = rb * 16 + rr;
    const float v = Cb[(size_t)r * 1024 + cx];
    L[r][cx] = v;
    part = fmaf(v, W0[d0 + r], part);
    Corig[((size_t)b * 512 + d0 + r) * 1024 + i0 + cx] = f2bf(v);
  }
  P[rb][cx] = part;
  __syncthreads();
#pragma unroll
  for (int rr = 0; rr < 16; ++rr) {
    const int il = rb * 16 + rr;
    O[((size_t)b * 1024 + i0 + il) * 2048 + d0 + cx] = f2bf(L[cx][il]);
  }
  if (rb == 0)
    atomicAdd(&cb[b * 1024 + i0 + cx], P[0][cx] + P[1][cx] + P[2][cx] + P[3][cx]);
}

// ---- prep: Q -> Qmb = (Q_t * w_m) bf16, Qorig bf16, qbias atomic -----------
__global__ __launch_bounds__(256) void prep_Q(const float* __restrict__ Q,
                                              const float* __restrict__ W0,
                                              u16* __restrict__ Qmb,
                                              u16* __restrict__ Qorig,
                                              float* __restrict__ qb) {
  __shared__ float L[64][65];
  __shared__ float P[4][64];
  const int b = blockIdx.z;
  const int d0 = blockIdx.y * 64;
  const int j0 = blockIdx.x * 64;
  const int t = threadIdx.x;
  const int cx = t & 63;
  const int rb = t >> 6;
  const float* Qb = Q + ((size_t)b * 512 + d0) * 128 + j0;
  float part = 0.f;
#pragma unroll
  for (int rr = 0; rr < 16; ++rr) {
    const int r = rb * 16 + rr;
    const float v = Qb[(size_t)r * 128 + cx];
    L[r][cx] = v;
    part = fmaf(v, W0[512 + d0 + r], part);
    Qorig[((size_t)b * 512 + d0 + r) * 128 + j0 + cx] = f2bf(v);
  }
  P[rb][cx] = part;
  __syncthreads();
  const float wm = W0[1024 + d0 + cx];
#pragma unroll
  for (int rr = 0; rr < 16; ++rr) {
    const int jl = rb * 16 + rr;
    Qmb[((size_t)b * 128 + j0 + jl) * 512 + d0 + cx] = f2bf(L[cx][jl] * wm);
  }
  if (rb == 0)
    atomicAdd(&qb[b * 128 + j0 + cx], P[0][cx] + P[1][cx] + P[2][cx] + P[3][cx]);
}

// ---- Wr fp32 -> bf16 -------------------------------------------------------
__global__ __launch_bounds__(256) void cvt_wr(const float* __restrict__ Wr,
                                              u16* __restrict__ Wrb) {
  const int idx = blockIdx.x * 256 + threadIdx.x;
  const float4 v = ((const float4*)Wr)[idx];
  short4v o;
  o[0] = (short)f2bf(v.x);
  o[1] = (short)f2bf(v.y);
  o[2] = (short)f2bf(v.z);
  o[3] = (short)f2bf(v.w);
  *(short4v*)&Wrb[(size_t)idx * 4] = o;
}

extern "C" void kernel_launch(void* const* d_in, const int* in_sizes, int n_in,
                              void* d_out, int out_size, void* d_ws, size_t ws_size,
                              hipStream_t stream) {
  (void)in_sizes; (void)n_in; (void)out_size;
  const float* C = (const float*)d_in[0];
  const float* Q = (const float*)d_in[1];
  const float* cm = (const float*)d_in[2];
  const float* qm = (const float*)d_in[3];
  const float* W0 = (const float*)d_in[4];
  const float* Wr = (const float*)d_in[5];
  float* out = (float*)d_out;

  if (ws_size < 405078016ull) return;  // ~386 MiB scratch

  char* p = (char*)d_ws;
  u16* O     = (u16*)(p);                    // (B,1024,2048) bf16 [C_t|A|C*A|C*Bm]
  u16* Corig = (u16*)(p + 268435456ull);     // (B,512,1024) bf16
  u16* Qmb   = (u16*)(p + 335544320ull);     // (B,128,512)  bf16
  u16* Qorig = (u16*)(p + 343932928ull);     // (B,512,128)  bf16
  u16* EunT  = (u16*)(p + 360710144ull);     // (B,128,1024) bf16 unnorm col-exp^T
  u16* Sbar  = (u16*)(p + 377487360ull);     // (B,1024,128) bf16
  u16* Wrb   = (u16*)(p + 402653184ull);     // (512,2048)   bf16
  float* cb  = (float*)(p + 404750336ull);   // (B,1024)
  float* qb  = (float*)(p + 405012480ull);   // (B,128)
  float* csum= (float*)(p + 405045248ull);   // (B,128)

  (void)hipFuncSetAttribute((const void*)gemm8b,
                            hipFuncAttributeMaxDynamicSharedMemorySize, 163840);
  (void)hipFuncSetAttribute((const void*)gemm_tab,
                            hipFuncAttributeMaxDynamicSharedMemorySize, 163840);
  (void)hipMemsetAsync(cb, 0, 327680, stream);  // cb + qb + csum contiguous

  cvt_wr<<<dim3(1024), dim3(256), 0, stream>>>(Wr, Wrb);
  prep_C<<<dim3(16, 8, 64), dim3(256), 0, stream>>>(C, W0, O, Corig, cb);
  prep_Q<<<dim3(2, 8, 64), dim3(256), 0, stream>>>(Q, W0, Qmb, Qorig, qb);

  // S-GEMM + fused row softmax + transposed unnormalized col-exp
  gemm_s<<<dim3(8, 1, 64), dim3(256), 0, stream>>>(O, Qmb, cb, qb, cm, qm,
                                                   Sbar, EunT, csum);

  // merged T-GEMM + A/Bm GEMM: chunks 1,2,3 of O (T never materialized)
  gemm_tab<<<dim3(4, 64), dim3(512), 163840, stream>>>(EunT, Corig, csum,
                                                       Sbar, Qorig, O);

  // R = Wr @ out^T : flat M=512, N=65536, K=2048; 16-wave 256^2
  gemm8b<<<dim3(512), dim3(1024), 163840, stream>>>(Wrb, O, out);
}

// Round 12
// 339.800 us; speedup vs baseline: 1.6080x; 1.0329x over previous
//
#include <hip/hip_runtime.h>
#include <hip/hip_bf16.h>

typedef unsigned short u16;
typedef __attribute__((ext_vector_type(8))) short short8;
typedef __attribute__((ext_vector_type(4))) short short4v;
typedef __attribute__((ext_vector_type(4))) float f32x4;

#define NEGV -1000000000000000.0f
#define SBAR() asm volatile("s_barrier" ::: "memory")

__device__ __forceinline__ u16 f2bf(float f) {
  unsigned u = __float_as_uint(f);
  unsigned r = (u + 0x7FFFu + ((u >> 16) & 1u)) >> 16;
  return (u16)r;
}
__device__ __forceinline__ float bf2f(u16 s) {
  return __uint_as_float(((unsigned)s) << 16);
}
__device__ __forceinline__ void lds16(const void* g, void* l) {
  __builtin_amdgcn_global_load_lds((const __attribute__((address_space(1))) void*)g,
                                   (__attribute__((address_space(3))) void*)l,
                                   16, 0, 0);
}

// ============ 256x256 GEMM, 16 waves (4Mx4N, 64x64/wave): out = Wrb @ O^T ===
// (r8 verified, 148us.) LDS 160KB: A dbuf 2x32K + B 3-buf 3x32K.
// 2 phases/K-tile; stage A(t+1)@p0, B(t+2)@p1; uniform vmcnt(2)@p1.
__global__ __launch_bounds__(1024) void gemm8b(const u16* __restrict__ A,
                                               const u16* __restrict__ B,
                                               float* __restrict__ out) {
  extern __shared__ u16 lds[];
  const int bid = blockIdx.x;
  const int wg = (bid & 7) * 64 + (bid >> 3);  // m-pair shares B-tile on one XCD
  const int m0 = (wg & 1) * 256;
  const int n0 = (wg >> 1) * 256;
  const int tid = threadIdx.x;
  const int lane = tid & 63;
  const int w = tid >> 6;   // 0..15
  const int wr = w >> 2;    // 64-row band
  const int wc = w & 3;     // 64-col band
  const int fro = lane & 15;
  const int hi = lane >> 4;
  const int kx = fro & 7;
  const int sr = lane >> 3;
  const int sgc = ((lane & 7) ^ sr) << 3;  // pre-swizzled source col (elems)

  const u16* Ag = A + (size_t)m0 * 2048;
  const u16* Bg = B + (size_t)n0 * 2048;
  const int rA = wr * 64 + fro;
  const int rB = wc * 64 + fro;

  f32x4 acc[4][4] = {};

#define STG(gp, lp) \
  lds16((gp) + (size_t)(w * 8 + sr) * 2048 + sgc, (u16*)(lp) + w * 512)
#define RDF(base, row, k16) \
  (*(const short8*)&(base)[(size_t)(row) * 64 + (((k16) ^ kx) << 3)])

  // prologue: A0, B0, B1
  STG(Ag, lds);
  STG(Ag + 262144, lds + 8192);
  STG(Bg, lds + 32768);
  STG(Bg + 262144, lds + 32768 + 8192);
  STG(Bg + 64, lds + 49152);
  STG(Bg + 262144 + 64, lds + 57344);
  asm volatile("s_waitcnt vmcnt(2)" ::: "memory");  // A0,B0 done; B1 in flight
  SBAR();

  const u16* Ac = lds;
  u16* An = lds + 16384;
  const u16* Bc = lds + 32768;   // B(t)
  const u16* Bn = lds + 49152;   // B(t+1)
  u16* Bs2 = lds + 65536;        // stage target B(t+2)

  for (int t = 0; t < 32; ++t) {
    const int kkA = (t < 31 ? t + 1 : 31) * 64;
    const int kkB = (t < 30 ? t + 2 : 31) * 64;
    short8 af[4], bf[4];

    // ---- phase 0 (ks=0): 8 ds_read; stage A(t+1); 16 MFMA
#pragma unroll
    for (int i = 0; i < 4; ++i) af[i] = RDF(Ac, rA + i * 16, hi);
#pragma unroll
    for (int j = 0; j < 4; ++j) bf[j] = RDF(Bc, rB + j * 16, hi);
    STG(Ag + kkA, An);
    STG(Ag + 262144 + kkA, An + 8192);
    SBAR();
    __builtin_amdgcn_s_setprio(1);
#pragma unroll
    for (int i = 0; i < 4; ++i)
#pragma unroll
      for (int j = 0; j < 4; ++j)
        acc[i][j] =
            __builtin_amdgcn_mfma_f32_16x16x32_bf16(af[i], bf[j], acc[i][j], 0, 0, 0);
    __builtin_amdgcn_s_setprio(0);
    SBAR();

    // ---- phase 1 (ks=1): 8 ds_read; stage B(t+2); vmcnt(2); 16 MFMA
#pragma unroll
    for (int i = 0; i < 4; ++i) af[i] = RDF(Ac, rA + i * 16, 4 + hi);
#pragma unroll
    for (int j = 0; j < 4; ++j) bf[j] = RDF(Bc, rB + j * 16, 4 + hi);
    STG(Bg + kkB, Bs2);
    STG(Bg + 262144 + kkB, Bs2 + 8192);
    asm volatile("s_waitcnt vmcnt(2)" ::: "memory");  // drain B(t+1), A(t+1)
    SBAR();
    __builtin_amdgcn_s_setprio(1);
#pragma unroll
    for (int i = 0; i < 4; ++i)
#pragma unroll
      for (int j = 0; j < 4; ++j)
        acc[i][j] =
            __builtin_amdgcn_mfma_f32_16x16x32_bf16(af[i], bf[j], acc[i][j], 0, 0, 0);
    __builtin_amdgcn_s_setprio(0);
    SBAR();

    // rotate buffers
    u16* tA = An; An = (u16*)Ac; Ac = tA;
    u16* tB = (u16*)Bc; Bc = Bn; Bn = Bs2; Bs2 = tB;
  }
  asm volatile("s_waitcnt vmcnt(0)" ::: "memory");

  // ---- epilogue: out[b][r][c], n = n0 + wc*64 + j*16 + fro
  const int crow = m0 + wr * 64 + hi * 4;
#pragma unroll
  for (int i = 0; i < 4; ++i)
#pragma unroll
    for (int j = 0; j < 4; ++j) {
      const int n = n0 + wc * 64 + j * 16 + fro;
      float* op = out + (size_t)(n >> 10) * 524288 + (n & 1023);
#pragma unroll
      for (int g = 0; g < 4; ++g)
        op[(size_t)(crow + i * 16 + g) * 1024] = acc[i][j][g];
    }
#undef STG
#undef RDF
}

// ============ S-GEMM + fused dual softmax + transposed-Eun epilogue =========
// K-loop staging double-buffered with counted vmcnt (r12).
__global__ __launch_bounds__(256) void gemm_s(
    const u16* __restrict__ A, const u16* __restrict__ Bq,
    const float* __restrict__ cb, const float* __restrict__ qb,
    const float* __restrict__ cmask, const float* __restrict__ qmask,
    u16* __restrict__ Sbar, u16* __restrict__ EunT, float* __restrict__ csum) {
  __shared__ u16 As[2][128 * 64];
  __shared__ u16 Bs[2][128 * 64];
  __shared__ u16 Lt[128][136];
  __shared__ float rmaxs[2][128];
  __shared__ float rsums[2][128];
  __shared__ float cparts[2][128];
  const int b = blockIdx.z;
  const int m0 = blockIdx.x * 128;
  const u16* Ab = A + (size_t)b * 2097152;
  const u16* Bb = Bq + (size_t)b * 65536;
  const int t = threadIdx.x;
  const int lane = t & 63;
  const int w = t >> 6;
  const int wr = w >> 1, wc = w & 1;
  const int srow = lane >> 3;
  const int scol = (lane & 7) * 8;

  f32x4 acc[4][4] = {};

#define SSTG(k0, sel)                                                         \
  {                                                                           \
    _Pragma("unroll") for (int qq = 0; qq < 4; ++qq) {                        \
      const int q = w * 4 + qq;                                               \
      const int r = q * 8 + srow;                                             \
      lds16(Ab + (size_t)(m0 + r) * 2048 + (k0) + scol, &As[sel][q * 512]);   \
      lds16(Bb + (size_t)r * 512 + (k0) + scol, &Bs[sel][q * 512]);           \
    }                                                                         \
  }

  SSTG(0, 0);
  for (int it = 0; it < 8; ++it) {
    if (it < 7) {
      SSTG((it + 1) * 64, (it + 1) & 1);
      asm volatile("s_waitcnt vmcnt(8)" ::: "memory");  // drain tile it only
    } else {
      asm volatile("s_waitcnt vmcnt(0)" ::: "memory");
    }
    SBAR();
    const u16* Asc = As[it & 1];
    const u16* Bsc = Bs[it & 1];
#pragma unroll
    for (int ks = 0; ks < 2; ++ks) {
      short8 af[4], bg[4];
      const int fro = lane & 15;
      const int k8 = ks * 32 + (lane >> 4) * 8;
#pragma unroll
      for (int i = 0; i < 4; ++i)
        af[i] = *(const short8*)&Asc[(wr * 64 + i * 16 + fro) * 64 + k8];
#pragma unroll
      for (int i = 0; i < 4; ++i)
        bg[i] = *(const short8*)&Bsc[(wc * 64 + i * 16 + fro) * 64 + k8];
#pragma unroll
      for (int i = 0; i < 4; ++i)
#pragma unroll
        for (int j = 0; j < 4; ++j)
          acc[i][j] =
              __builtin_amdgcn_mfma_f32_16x16x32_bf16(af[i], bg[j], acc[i][j], 0, 0, 0);
    }
    SBAR();
  }
#undef SSTG

  const int fro = lane & 15;
  const int hi = lane >> 4;
  float qv[4], qbv[4];
#pragma unroll
  for (int j = 0; j < 4; ++j) {
    const int cc = wc * 64 + j * 16 + fro;
    qv[j] = qmask[b * 128 + cc];
    qbv[j] = qb[b * 128 + cc];
  }
  float colp[4] = {0.f, 0.f, 0.f, 0.f};
#pragma unroll
  for (int i = 0; i < 4; ++i)
#pragma unroll
    for (int g = 0; g < 4; ++g) {
      const int rl = wr * 64 + i * 16 + hi * 4 + g;
      const float rb = cb[b * 1024 + m0 + rl];
      const float cv = cmask[b * 1024 + m0 + rl];
      const float coff = NEGV * (1.f - cv);
#pragma unroll
      for (int j = 0; j < 4; ++j) {
        const float v = acc[i][j][g] + rb + qbv[j];
        acc[i][j][g] = v;
        const float e = __expf(v * cv + coff);
        Lt[wc * 64 + j * 16 + fro][rl] = f2bf(e);
        colp[j] += e;
      }
    }
#pragma unroll
  for (int j = 0; j < 4; ++j) {
    colp[j] += __shfl_xor(colp[j], 16);
    colp[j] += __shfl_xor(colp[j], 32);
  }
  if (hi == 0)
#pragma unroll
    for (int j = 0; j < 4; ++j) cparts[wr][wc * 64 + j * 16 + fro] = colp[j];
  float rtmp[4][4];
#pragma unroll
  for (int i = 0; i < 4; ++i)
#pragma unroll
    for (int g = 0; g < 4; ++g) {
      float m = -3.4e38f;
#pragma unroll
      for (int j = 0; j < 4; ++j) {
        const float xm = acc[i][j][g] * qv[j] + NEGV * (1.f - qv[j]);
        acc[i][j][g] = xm;
        m = fmaxf(m, xm);
      }
#pragma unroll
      for (int o = 8; o; o >>= 1) m = fmaxf(m, __shfl_xor(m, o));
      rtmp[i][g] = m;
    }
  if (fro == 0)
#pragma unroll
    for (int i = 0; i < 4; ++i)
#pragma unroll
      for (int g = 0; g < 4; ++g)
        rmaxs[wc][wr * 64 + i * 16 + hi * 4 + g] = rtmp[i][g];
  __syncthreads();
  if (t < 128) atomicAdd(&csum[b * 128 + t], cparts[0][t] + cparts[1][t]);
  {
    const int jr = t >> 1;
    const int ih = (t & 1) * 64;
    u16* dst = EunT + (size_t)b * 131072 + (size_t)jr * 1024 + m0 + ih;
#pragma unroll
    for (int s = 0; s < 8; ++s)
      *(short8*)(dst + s * 8) = *(const short8*)&Lt[jr][ih + s * 8];
  }
#pragma unroll
  for (int i = 0; i < 4; ++i)
#pragma unroll
    for (int g = 0; g < 4; ++g) {
      const int rl = wr * 64 + i * 16 + hi * 4 + g;
      const float M = fmaxf(rmaxs[0][rl], rmaxs[1][rl]);
      float s = 0.f;
#pragma unroll
      for (int j = 0; j < 4; ++j) {
        const float p = __expf(acc[i][j][g] - M);
        acc[i][j][g] = p;
        s += p;
      }
#pragma unroll
      for (int o = 8; o; o >>= 1) s += __shfl_xor(s, o);
      rtmp[i][g] = s;
    }
  if (fro == 0)
#pragma unroll
    for (int i = 0; i < 4; ++i)
#pragma unroll
      for (int g = 0; g < 4; ++g)
        rsums[wc][wr * 64 + i * 16 + hi * 4 + g] = rtmp[i][g];
  __syncthreads();
#pragma unroll
  for (int i = 0; i < 4; ++i)
#pragma unroll
    for (int g = 0; g < 4; ++g) {
      const int rl = wr * 64 + i * 16 + hi * 4 + g;
      const float inv = 1.f / (rsums[0][rl] + rsums[1][rl]);
#pragma unroll
      for (int j = 0; j < 4; ++j)
        Sbar[((size_t)b * 1024 + m0 + rl) * 128 + wc * 64 + j * 16 + fro] =
            f2bf(acc[i][j][g] * inv);
    }
}

// ============ merged T-GEMM + A/Bm GEMM: grid (dcol, b), 512 thr, 160KB =====
// Phase T (dbuf-staged, counted vmcnt): T_tile = (EunT @ Corig[dcol]^T)/csum
// -> LT (swizzled, never global). Phase AB: Qo/LT LDS-resident, Sbar dbuf
// prefetch, chunks 1,2,3 of O with fused C_t products.
// LDS map (u16 idx): LQ[0,16384) LT[16384,32768) Tstage[32768,65536) (2 bufs
// TA+TB; reused as LS dbuf in phase AB) Ls[65536,81920).
__global__ __launch_bounds__(512) void gemm_tab(
    const u16* __restrict__ EunT, const u16* __restrict__ Corig,
    const float* __restrict__ csum, const u16* __restrict__ Sbar,
    const u16* __restrict__ Qo, u16* __restrict__ O) {
  extern __shared__ u16 sh[];
  u16* LQ = sh;             // 32KB Qo tile
  u16* LT = sh + 16384;     // 32KB T tile
  u16* Ls = sh + 65536;     // 32KB epilogue scratch
  const int dcol = blockIdx.x * 128;
  const int b = blockIdx.y;
  const int t = threadIdx.x;
  const int lane = t & 63;
  const int w = t >> 6;
  const int wr = w >> 2, wc = w & 3;
  const int fro = lane & 15, hi = lane >> 4;
  const int srow4 = t >> 4;   // 0..31
  const int sslot = t & 15;   // 16B slot

#define STG32(gp, lp)                                                         \
  {                                                                           \
    _Pragma("unroll") for (int ii = 0; ii < 4; ++ii) {                        \
      const int row_ = ii * 32 + srow4;                                       \
      lds16((gp) + (size_t)row_ * 128 + ((sslot ^ (row_ & 7)) << 3),          \
            (u16*)(lp) + ii * 4096 + t * 8);                                  \
    }                                                                         \
  }
#define RDS(base, row, kslot)                                                 \
  (*(const short8*)&(base)[(size_t)(row) * 128 + (((kslot) ^ ((row) & 7)) << 3)])
// stage a 128x64 bf16 K-tile (linear layout [row][64]), 2 gloads/thread
#define TSTG(gp, lp)                                                          \
  {                                                                           \
    _Pragma("unroll") for (int q = 0; q < 2; ++q) {                           \
      const int row_ = q * 64 + (t >> 3);                                     \
      lds16((gp) + (size_t)row_ * 1024 + ((t & 7) << 3),                      \
            (u16*)(lp) + q * 4096 + t * 8);                                   \
    }                                                                         \
  }

  // ---- issue LQ stage early; drains at phase T's first counted vmcnt
  STG32(Qo + (size_t)b * 65536 + (size_t)dcol * 128, LQ);

  // ================= phase T (double-buffered staging) =================
  {
    const u16* Ag = EunT + (size_t)b * 131072;                       // [128j][1024i]
    const u16* Bg = Corig + (size_t)b * 524288 + (size_t)dcol * 1024;// [128d][1024i]
    f32x4 acc[4][2] = {};
    TSTG(Ag, sh + 32768);          // TA0
    TSTG(Bg, sh + 40960);          // TB0
    for (int k = 0; k < 16; ++k) {
      if (k < 15) {
        u16* nb = sh + 32768 + ((k + 1) & 1) * 16384;
        TSTG(Ag + (k + 1) * 64, nb);
        TSTG(Bg + (k + 1) * 64, nb + 8192);
        asm volatile("s_waitcnt vmcnt(4)" ::: "memory");  // drain tile k (+LQ @k=0)
      } else {
        asm volatile("s_waitcnt vmcnt(0)" ::: "memory");
      }
      SBAR();
      const u16* TAc = sh + 32768 + (k & 1) * 16384;
      const u16* TBc = TAc + 8192;
#pragma unroll
      for (int ks = 0; ks < 2; ++ks) {
        short8 af[4], bg[2];
        const int k8 = ks * 32 + hi * 8;
#pragma unroll
        for (int i = 0; i < 4; ++i)
          af[i] = *(const short8*)&TAc[(wr * 64 + i * 16 + fro) * 64 + k8];
#pragma unroll
        for (int jf = 0; jf < 2; ++jf)
          bg[jf] = *(const short8*)&TBc[(wc * 32 + jf * 16 + fro) * 64 + k8];
#pragma unroll
        for (int i = 0; i < 4; ++i)
#pragma unroll
          for (int jf = 0; jf < 2; ++jf)
            acc[i][jf] = __builtin_amdgcn_mfma_f32_16x16x32_bf16(
                af[i], bg[jf], acc[i][jf], 0, 0, 0);
      }
      SBAR();
    }
    // T epilogue: scale by 1/csum[j], write LT in ab-swizzled layout
    const int col = lane & 15;
    const int r4 = hi * 4;
#pragma unroll
    for (int i = 0; i < 4; ++i)
#pragma unroll
      for (int g = 0; g < 4; ++g) {
        const int j = wr * 64 + i * 16 + r4 + g;
        const float inv = 1.f / csum[b * 128 + j];
#pragma unroll
        for (int jf = 0; jf < 2; ++jf) {
          const int d = wc * 32 + jf * 16 + col;
          LT[d * 128 + (((j >> 3) ^ (d & 7)) << 3) + (j & 7)] =
              f2bf(acc[i][jf][g] * inv);
        }
      }
  }
  __syncthreads();  // LT visible; Tstage region free for LS dbuf reuse

  // ================= phase AB =================
  const u16* Sg = Sbar + (size_t)b * 131072;
  STG32(Sg, sh + 32768);
  asm volatile("s_waitcnt vmcnt(0)" ::: "memory");
  __syncthreads();

  for (int mm = 0; mm < 8; ++mm) {
    const u16* LSc = sh + 32768 + ((size_t)(mm & 1) << 14);
    u16* LSn = sh + 32768 + ((size_t)((mm + 1) & 1) << 14);
    if (mm < 7) STG32(Sg + (size_t)(mm + 1) * 16384, LSn);

    f32x4 aa[4][2] = {};
    f32x4 ab[4][2] = {};
#pragma unroll
    for (int ks = 0; ks < 4; ++ks) {
      short8 af[4], bq[2], bt[2];
#pragma unroll
      for (int i = 0; i < 4; ++i) {
        const int r = wr * 64 + i * 16 + fro;
        af[i] = RDS(LSc, r, ks * 4 + hi);
      }
#pragma unroll
      for (int j = 0; j < 2; ++j) {
        const int r = wc * 32 + j * 16 + fro;
        bq[j] = RDS(LQ, r, ks * 4 + hi);
        bt[j] = RDS(LT, r, ks * 4 + hi);
      }
#pragma unroll
      for (int i = 0; i < 4; ++i)
#pragma unroll
        for (int j = 0; j < 2; ++j) {
          aa[i][j] =
              __builtin_amdgcn_mfma_f32_16x16x32_bf16(af[i], bq[j], aa[i][j], 0, 0, 0);
          ab[i][j] =
              __builtin_amdgcn_mfma_f32_16x16x32_bf16(af[i], bt[j], ab[i][j], 0, 0, 0);
        }
    }

    const size_t obase = (size_t)b * 2097152 + (size_t)mm * 262144 + dcol;
    __syncthreads();  // drains prefetch too
#pragma unroll
    for (int i = 0; i < 4; ++i)
#pragma unroll
      for (int j = 0; j < 2; ++j)
#pragma unroll
        for (int g = 0; g < 4; ++g)
          Ls[(wr * 64 + i * 16 + hi * 4 + g) * 128 + wc * 32 + j * 16 + fro] =
              f2bf(aa[i][j][g]);
    __syncthreads();
    short8 c8[4];
#pragma unroll
    for (int it = 0; it < 4; ++it) {
      const int row = it * 32 + srow4;
      const short8 a8 = *(const short8*)&Ls[row * 128 + sslot * 8];
      c8[it] = *(const short8*)&O[obase + (size_t)row * 2048 + sslot * 8];
      short8 p2;
#pragma unroll
      for (int k = 0; k < 8; ++k)
        p2[k] = (short)f2bf(bf2f((u16)c8[it][k]) * bf2f((u16)a8[k]));
      *(short8*)&O[obase + (size_t)row * 2048 + sslot * 8 + 512] = a8;
      *(short8*)&O[obase + (size_t)row * 2048 + sslot * 8 + 1024] = p2;
    }
    __syncthreads();
#pragma unroll
    for (int i = 0; i < 4; ++i)
#pragma unroll
      for (int j = 0; j < 2; ++j)
#pragma unroll
        for (int g = 0; g < 4; ++g)
          Ls[(wr * 64 + i * 16 + hi * 4 + g) * 128 + wc * 32 + j * 16 + fro] =
              f2bf(ab[i][j][g]);
    __syncthreads();
#pragma unroll
    for (int it = 0; it < 4; ++it) {
      const int row = it * 32 + srow4;
      const short8 b8 = *(const short8*)&Ls[row * 128 + sslot * 8];
      short8 p3;
#pragma unroll
      for (int k = 0; k < 8; ++k)
        p3[k] = (short)f2bf(bf2f((u16)c8[it][k]) * bf2f((u16)b8[k]));
      *(short8*)&O[obase + (size_t)row * 2048 + sslot * 8 + 1536] = p3;
    }
    __syncthreads();
  }
#undef STG32
#undef RDS
#undef TSTG
}

// ---- prep: C fp32 -> O chunk0 = C_t bf16 (ld 2048), Corig bf16, cbias atomic
__global__ __launch_bounds__(256) void prep_C(const float* __restrict__ C,
                                              const float* __restrict__ W0,
                                              u16* __restrict__ O,
                                              u16* __restrict__ Corig,
                                              float* __restrict__ cb) {
  __shared__ float L[64][65];
  __shared__ float P[4][64];
  const int b = blockIdx.z;
  const int d0 = blockIdx.y * 64;
  const int i0 = blockIdx.x * 64;
  const int t = threadIdx.x;
  const int cx = t & 63;
  const int rb = t >> 6;
  const float* Cb = C + ((size_t)b * 512 + d0) * 1024 + i0;
  float part = 0.f;
#pragma unroll
  for (int rr = 0; rr < 16; ++rr) {
    const int r = rb * 16 + rr;
    const float v = Cb[(size_t)r * 1024 + cx];
    L[r][cx] = v;
    part = fmaf(v, W0[d0 + r], part);
    Corig[((size_t)b * 512 + d0 + r) * 1024 + i0 + cx] = f2bf(v);
  }
  P[rb][cx] = part;
  __syncthreads();
#pragma unroll
  for (int rr = 0; rr < 16; ++rr) {
    const int il = rb * 16 + rr;
    O[((size_t)b * 1024 + i0 + il) * 2048 + d0 + cx] = f2bf(L[cx][il]);
  }
  if (rb == 0)
    atomicAdd(&cb[b * 1024 + i0 + cx], P[0][cx] + P[1][cx] + P[2][cx] + P[3][cx]);
}

// ---- prep: Q -> Qmb = (Q_t * w_m) bf16, Qorig bf16, qbias atomic -----------
__global__ __launch_bounds__(256) void prep_Q(const float* __restrict__ Q,
                                              const float* __restrict__ W0,
                                              u16* __restrict__ Qmb,
                                              u16* __restrict__ Qorig,
                                              float* __restrict__ qb) {
  __shared__ float L[64][65];
  __shared__ float P[4][64];
  const int b = blockIdx.z;
  const int d0 = blockIdx.y * 64;
  const int j0 = blockIdx.x * 64;
  const int t = threadIdx.x;
  const int cx = t & 63;
  const int rb = t >> 6;
  const float* Qb = Q + ((size_t)b * 512 + d0) * 128 + j0;
  float part = 0.f;
#pragma unroll
  for (int rr = 0; rr < 16; ++rr) {
    const int r = rb * 16 + rr;
    const float v = Qb[(size_t)r * 128 + cx];
    L[r][cx] = v;
    part = fmaf(v, W0[512 + d0 + r], part);
    Qorig[((size_t)b * 512 + d0 + r) * 128 + j0 + cx] = f2bf(v);
  }
  P[rb][cx] = part;
  __syncthreads();
  const float wm = W0[1024 + d0 + cx];
#pragma unroll
  for (int rr = 0; rr < 16; ++rr) {
    const int jl = rb * 16 + rr;
    Qmb[((size_t)b * 128 + j0 + jl) * 512 + d0 + cx] = f2bf(L[cx][jl] * wm);
  }
  if (rb == 0)
    atomicAdd(&qb[b * 128 + j0 + cx], P[0][cx] + P[1][cx] + P[2][cx] + P[3][cx]);
}

// ---- Wr fp32 -> bf16 -------------------------------------------------------
__global__ __launch_bounds__(256) void cvt_wr(const float* __restrict__ Wr,
                                              u16* __restrict__ Wrb) {
  const int idx = blockIdx.x * 256 + threadIdx.x;
  const float4 v = ((const float4*)Wr)[idx];
  short4v o;
  o[0] = (short)f2bf(v.x);
  o[1] = (short)f2bf(v.y);
  o[2] = (short)f2bf(v.z);
  o[3] = (short)f2bf(v.w);
  *(short4v*)&Wrb[(size_t)idx * 4] = o;
}

extern "C" void kernel_launch(void* const* d_in, const int* in_sizes, int n_in,
                              void* d_out, int out_size, void* d_ws, size_t ws_size,
                              hipStream_t stream) {
  (void)in_sizes; (void)n_in; (void)out_size;
  const float* C = (const float*)d_in[0];
  const float* Q = (const float*)d_in[1];
  const float* cm = (const float*)d_in[2];
  const float* qm = (const float*)d_in[3];
  const float* W0 = (const float*)d_in[4];
  const float* Wr = (const float*)d_in[5];
  float* out = (float*)d_out;

  if (ws_size < 405078016ull) return;  // ~386 MiB scratch

  char* p = (char*)d_ws;
  u16* O     = (u16*)(p);                    // (B,1024,2048) bf16 [C_t|A|C*A|C*Bm]
  u16* Corig = (u16*)(p + 268435456ull);     // (B,512,1024) bf16
  u16* Qmb   = (u16*)(p + 335544320ull);     // (B,128,512)  bf16
  u16* Qorig = (u16*)(p + 343932928ull);     // (B,512,128)  bf16
  u16* EunT  = (u16*)(p + 360710144ull);     // (B,128,1024) bf16 unnorm col-exp^T
  u16* Sbar  = (u16*)(p + 377487360ull);     // (B,1024,128) bf16
  u16* Wrb   = (u16*)(p + 402653184ull);     // (512,2048)   bf16
  float* cb  = (float*)(p + 404750336ull);   // (B,1024)
  float* qb  = (float*)(p + 405012480ull);   // (B,128)
  float* csum= (float*)(p + 405045248ull);   // (B,128)

  (void)hipFuncSetAttribute((const void*)gemm8b,
                            hipFuncAttributeMaxDynamicSharedMemorySize, 163840);
  (void)hipFuncSetAttribute((const void*)gemm_tab,
                            hipFuncAttributeMaxDynamicSharedMemorySize, 163840);
  (void)hipMemsetAsync(cb, 0, 327680, stream);  // cb + qb + csum contiguous

  cvt_wr<<<dim3(1024), dim3(256), 0, stream>>>(Wr, Wrb);
  prep_C<<<dim3(16, 8, 64), dim3(256), 0, stream>>>(C, W0, O, Corig, cb);
  prep_Q<<<dim3(2, 8, 64), dim3(256), 0, stream>>>(Q, W0, Qmb, Qorig, qb);

  // S-GEMM + fused row softmax + transposed unnormalized col-exp
  gemm_s<<<dim3(8, 1, 64), dim3(256), 0, stream>>>(O, Qmb, cb, qb, cm, qm,
                                                   Sbar, EunT, csum);

  // merged T-GEMM + A/Bm GEMM: chunks 1,2,3 of O (T never materialized)
  gemm_tab<<<dim3(4, 64), dim3(512), 163840, stream>>>(EunT, Corig, csum,
                                                       Sbar, Qorig, O);

  // R = Wr @ out^T : flat M=512, N=65536, K=2048; 16-wave 256^2
  gemm8b<<<dim3(512), dim3(1024), 163840, stream>>>(Wrb, O, out);
}

// Round 13
// 334.815 us; speedup vs baseline: 1.6320x; 1.0149x over previous
//
#include <hip/hip_runtime.h>
#include <hip/hip_bf16.h>

typedef unsigned short u16;
typedef __attribute__((ext_vector_type(8))) short short8;
typedef __attribute__((ext_vector_type(4))) short short4v;
typedef __attribute__((ext_vector_type(4))) float f32x4;

#define NEGV -1000000000000000.0f
#define SBAR() asm volatile("s_barrier" ::: "memory")

__device__ __forceinline__ u16 f2bf(float f) {
  unsigned u = __float_as_uint(f);
  unsigned r = (u + 0x7FFFu + ((u >> 16) & 1u)) >> 16;
  return (u16)r;
}
__device__ __forceinline__ float bf2f(u16 s) {
  return __uint_as_float(((unsigned)s) << 16);
}
__device__ __forceinline__ void lds16(const void* g, void* l) {
  __builtin_amdgcn_global_load_lds((const __attribute__((address_space(1))) void*)g,
                                   (__attribute__((address_space(3))) void*)l,
                                   16, 0, 0);
}

// ============ 256x256 GEMM, 16 waves (4Mx4N, 64x64/wave): out = Wrb @ O^T ===
// (r8 verified, 148us.) LDS 160KB: A dbuf 2x32K + B 3-buf 3x32K.
// 2 phases/K-tile; stage A(t+1)@p0, B(t+2)@p1; uniform vmcnt(2)@p1.
__global__ __launch_bounds__(1024) void gemm8b(const u16* __restrict__ A,
                                               const u16* __restrict__ B,
                                               float* __restrict__ out) {
  extern __shared__ u16 lds[];
  const int bid = blockIdx.x;
  const int wg = (bid & 7) * 64 + (bid >> 3);  // m-pair shares B-tile on one XCD
  const int m0 = (wg & 1) * 256;
  const int n0 = (wg >> 1) * 256;
  const int tid = threadIdx.x;
  const int lane = tid & 63;
  const int w = tid >> 6;   // 0..15
  const int wr = w >> 2;    // 64-row band
  const int wc = w & 3;     // 64-col band
  const int fro = lane & 15;
  const int hi = lane >> 4;
  const int kx = fro & 7;
  const int sr = lane >> 3;
  const int sgc = ((lane & 7) ^ sr) << 3;  // pre-swizzled source col (elems)

  const u16* Ag = A + (size_t)m0 * 2048;
  const u16* Bg = B + (size_t)n0 * 2048;
  const int rA = wr * 64 + fro;
  const int rB = wc * 64 + fro;

  f32x4 acc[4][4] = {};

#define STG(gp, lp) \
  lds16((gp) + (size_t)(w * 8 + sr) * 2048 + sgc, (u16*)(lp) + w * 512)
#define RDF(base, row, k16) \
  (*(const short8*)&(base)[(size_t)(row) * 64 + (((k16) ^ kx) << 3)])

  // prologue: A0, B0, B1
  STG(Ag, lds);
  STG(Ag + 262144, lds + 8192);
  STG(Bg, lds + 32768);
  STG(Bg + 262144, lds + 32768 + 8192);
  STG(Bg + 64, lds + 49152);
  STG(Bg + 262144 + 64, lds + 57344);
  asm volatile("s_waitcnt vmcnt(2)" ::: "memory");  // A0,B0 done; B1 in flight
  SBAR();

  const u16* Ac = lds;
  u16* An = lds + 16384;
  const u16* Bc = lds + 32768;   // B(t)
  const u16* Bn = lds + 49152;   // B(t+1)
  u16* Bs2 = lds + 65536;        // stage target B(t+2)

  for (int t = 0; t < 32; ++t) {
    const int kkA = (t < 31 ? t + 1 : 31) * 64;
    const int kkB = (t < 30 ? t + 2 : 31) * 64;
    short8 af[4], bf[4];

    // ---- phase 0 (ks=0): 8 ds_read; stage A(t+1); 16 MFMA
#pragma unroll
    for (int i = 0; i < 4; ++i) af[i] = RDF(Ac, rA + i * 16, hi);
#pragma unroll
    for (int j = 0; j < 4; ++j) bf[j] = RDF(Bc, rB + j * 16, hi);
    STG(Ag + kkA, An);
    STG(Ag + 262144 + kkA, An + 8192);
    SBAR();
    __builtin_amdgcn_s_setprio(1);
#pragma unroll
    for (int i = 0; i < 4; ++i)
#pragma unroll
      for (int j = 0; j < 4; ++j)
        acc[i][j] =
            __builtin_amdgcn_mfma_f32_16x16x32_bf16(af[i], bf[j], acc[i][j], 0, 0, 0);
    __builtin_amdgcn_s_setprio(0);
    SBAR();

    // ---- phase 1 (ks=1): 8 ds_read; stage B(t+2); vmcnt(2); 16 MFMA
#pragma unroll
    for (int i = 0; i < 4; ++i) af[i] = RDF(Ac, rA + i * 16, 4 + hi);
#pragma unroll
    for (int j = 0; j < 4; ++j) bf[j] = RDF(Bc, rB + j * 16, 4 + hi);
    STG(Bg + kkB, Bs2);
    STG(Bg + 262144 + kkB, Bs2 + 8192);
    asm volatile("s_waitcnt vmcnt(2)" ::: "memory");  // drain B(t+1), A(t+1)
    SBAR();
    __builtin_amdgcn_s_setprio(1);
#pragma unroll
    for (int i = 0; i < 4; ++i)
#pragma unroll
      for (int j = 0; j < 4; ++j)
        acc[i][j] =
            __builtin_amdgcn_mfma_f32_16x16x32_bf16(af[i], bf[j], acc[i][j], 0, 0, 0);
    __builtin_amdgcn_s_setprio(0);
    SBAR();

    // rotate buffers
    u16* tA = An; An = (u16*)Ac; Ac = tA;
    u16* tB = (u16*)Bc; Bc = Bn; Bn = Bs2; Bs2 = tB;
  }
  asm volatile("s_waitcnt vmcnt(0)" ::: "memory");

  // ---- epilogue: out[b][r][c], n = n0 + wc*64 + j*16 + fro
  const int crow = m0 + wr * 64 + hi * 4;
#pragma unroll
  for (int i = 0; i < 4; ++i)
#pragma unroll
    for (int j = 0; j < 4; ++j) {
      const int n = n0 + wc * 64 + j * 16 + fro;
      float* op = out + (size_t)(n >> 10) * 524288 + (n & 1023);
#pragma unroll
      for (int g = 0; g < 4; ++g)
        op[(size_t)(crow + i * 16 + g) * 1024] = acc[i][j][g];
    }
#undef STG
#undef RDF
}

// ============ S-GEMM + fused dual softmax + transposed-Eun epilogue =========
// dbuf counted-vmcnt staging; XCD-swizzled grid (8 m-tile sharers of Qmb[b]
// co-located per XCD for L2 reuse).
__global__ __launch_bounds__(256) void gemm_s(
    const u16* __restrict__ A, const u16* __restrict__ Bq,
    const float* __restrict__ cb, const float* __restrict__ qb,
    const float* __restrict__ cmask, const float* __restrict__ qmask,
    u16* __restrict__ Sbar, u16* __restrict__ EunT, float* __restrict__ csum) {
  __shared__ u16 As[2][128 * 64];
  __shared__ u16 Bs[2][128 * 64];
  __shared__ u16 Lt[128][136];
  __shared__ float rmaxs[2][128];
  __shared__ float rsums[2][128];
  __shared__ float cparts[2][128];
  const int bid = blockIdx.x;
  const int xcd = bid & 7;
  const int kk = bid >> 3;            // 0..63
  const int b = xcd * 8 + (kk >> 3);  // 8 m-tiles of one b share an XCD
  const int m0 = (kk & 7) * 128;
  const u16* Ab = A + (size_t)b * 2097152;
  const u16* Bb = Bq + (size_t)b * 65536;
  const int t = threadIdx.x;
  const int lane = t & 63;
  const int w = t >> 6;
  const int wr = w >> 1, wc = w & 1;
  const int srow = lane >> 3;
  const int scol = (lane & 7) * 8;

  f32x4 acc[4][4] = {};

#define SSTG(k0, sel)                                                         \
  {                                                                           \
    _Pragma("unroll") for (int qq = 0; qq < 4; ++qq) {                        \
      const int q = w * 4 + qq;                                               \
      const int r = q * 8 + srow;                                             \
      lds16(Ab + (size_t)(m0 + r) * 2048 + (k0) + scol, &As[sel][q * 512]);   \
      lds16(Bb + (size_t)r * 512 + (k0) + scol, &Bs[sel][q * 512]);           \
    }                                                                         \
  }

  SSTG(0, 0);
  for (int it = 0; it < 8; ++it) {
    if (it < 7) {
      SSTG((it + 1) * 64, (it + 1) & 1);
      asm volatile("s_waitcnt vmcnt(8)" ::: "memory");  // drain tile it only
    } else {
      asm volatile("s_waitcnt vmcnt(0)" ::: "memory");
    }
    SBAR();
    const u16* Asc = As[it & 1];
    const u16* Bsc = Bs[it & 1];
#pragma unroll
    for (int ks = 0; ks < 2; ++ks) {
      short8 af[4], bg[4];
      const int fro = lane & 15;
      const int k8 = ks * 32 + (lane >> 4) * 8;
#pragma unroll
      for (int i = 0; i < 4; ++i)
        af[i] = *(const short8*)&Asc[(wr * 64 + i * 16 + fro) * 64 + k8];
#pragma unroll
      for (int i = 0; i < 4; ++i)
        bg[i] = *(const short8*)&Bsc[(wc * 64 + i * 16 + fro) * 64 + k8];
#pragma unroll
      for (int i = 0; i < 4; ++i)
#pragma unroll
        for (int j = 0; j < 4; ++j)
          acc[i][j] =
              __builtin_amdgcn_mfma_f32_16x16x32_bf16(af[i], bg[j], acc[i][j], 0, 0, 0);
    }
    SBAR();
  }
#undef SSTG

  const int fro = lane & 15;
  const int hi = lane >> 4;
  float qv[4], qbv[4];
#pragma unroll
  for (int j = 0; j < 4; ++j) {
    const int cc = wc * 64 + j * 16 + fro;
    qv[j] = qmask[b * 128 + cc];
    qbv[j] = qb[b * 128 + cc];
  }
  float colp[4] = {0.f, 0.f, 0.f, 0.f};
#pragma unroll
  for (int i = 0; i < 4; ++i)
#pragma unroll
    for (int g = 0; g < 4; ++g) {
      const int rl = wr * 64 + i * 16 + hi * 4 + g;
      const float rb = cb[b * 1024 + m0 + rl];
      const float cv = cmask[b * 1024 + m0 + rl];
      const float coff = NEGV * (1.f - cv);
#pragma unroll
      for (int j = 0; j < 4; ++j) {
        const float v = acc[i][j][g] + rb + qbv[j];
        acc[i][j][g] = v;
        const float e = __expf(v * cv + coff);
        Lt[wc * 64 + j * 16 + fro][rl] = f2bf(e);
        colp[j] += e;
      }
    }
#pragma unroll
  for (int j = 0; j < 4; ++j) {
    colp[j] += __shfl_xor(colp[j], 16);
    colp[j] += __shfl_xor(colp[j], 32);
  }
  if (hi == 0)
#pragma unroll
    for (int j = 0; j < 4; ++j) cparts[wr][wc * 64 + j * 16 + fro] = colp[j];
  float rtmp[4][4];
#pragma unroll
  for (int i = 0; i < 4; ++i)
#pragma unroll
    for (int g = 0; g < 4; ++g) {
      float m = -3.4e38f;
#pragma unroll
      for (int j = 0; j < 4; ++j) {
        const float xm = acc[i][j][g] * qv[j] + NEGV * (1.f - qv[j]);
        acc[i][j][g] = xm;
        m = fmaxf(m, xm);
      }
#pragma unroll
      for (int o = 8; o; o >>= 1) m = fmaxf(m, __shfl_xor(m, o));
      rtmp[i][g] = m;
    }
  if (fro == 0)
#pragma unroll
    for (int i = 0; i < 4; ++i)
#pragma unroll
      for (int g = 0; g < 4; ++g)
        rmaxs[wc][wr * 64 + i * 16 + hi * 4 + g] = rtmp[i][g];
  __syncthreads();
  if (t < 128) atomicAdd(&csum[b * 128 + t], cparts[0][t] + cparts[1][t]);
  {
    const int jr = t >> 1;
    const int ih = (t & 1) * 64;
    u16* dst = EunT + (size_t)b * 131072 + (size_t)jr * 1024 + m0 + ih;
#pragma unroll
    for (int s = 0; s < 8; ++s)
      *(short8*)(dst + s * 8) = *(const short8*)&Lt[jr][ih + s * 8];
  }
#pragma unroll
  for (int i = 0; i < 4; ++i)
#pragma unroll
    for (int g = 0; g < 4; ++g) {
      const int rl = wr * 64 + i * 16 + hi * 4 + g;
      const float M = fmaxf(rmaxs[0][rl], rmaxs[1][rl]);
      float s = 0.f;
#pragma unroll
      for (int j = 0; j < 4; ++j) {
        const float p = __expf(acc[i][j][g] - M);
        acc[i][j][g] = p;
        s += p;
      }
#pragma unroll
      for (int o = 8; o; o >>= 1) s += __shfl_xor(s, o);
      rtmp[i][g] = s;
    }
  if (fro == 0)
#pragma unroll
    for (int i = 0; i < 4; ++i)
#pragma unroll
      for (int g = 0; g < 4; ++g)
        rsums[wc][wr * 64 + i * 16 + hi * 4 + g] = rtmp[i][g];
  __syncthreads();
#pragma unroll
  for (int i = 0; i < 4; ++i)
#pragma unroll
    for (int g = 0; g < 4; ++g) {
      const int rl = wr * 64 + i * 16 + hi * 4 + g;
      const float inv = 1.f / (rsums[0][rl] + rsums[1][rl]);
#pragma unroll
      for (int j = 0; j < 4; ++j)
        Sbar[((size_t)b * 1024 + m0 + rl) * 128 + wc * 64 + j * 16 + fro] =
            f2bf(acc[i][j][g] * inv);
    }
}

// ============ merged T-GEMM + A/Bm GEMM: XCD-swizzled grid (4 dcol sharers
// of EunT[b]/Sbar[b] co-located per XCD), 512 thr, 160KB =====================
__global__ __launch_bounds__(512) void gemm_tab(
    const u16* __restrict__ EunT, const u16* __restrict__ Corig,
    const float* __restrict__ csum, const u16* __restrict__ Sbar,
    const u16* __restrict__ Qo, u16* __restrict__ O) {
  extern __shared__ u16 sh[];
  u16* LQ = sh;             // 32KB Qo tile
  u16* LT = sh + 16384;     // 32KB T tile
  u16* Ls = sh + 65536;     // 32KB epilogue scratch
  const int bid = blockIdx.x;
  const int xcd = bid & 7;
  const int kb = bid >> 3;            // 0..31
  const int b = xcd * 8 + (kb >> 2);  // 4 dcol-blocks of one b share an XCD
  const int dcol = (kb & 3) * 128;
  const int t = threadIdx.x;
  const int lane = t & 63;
  const int w = t >> 6;
  const int wr = w >> 2, wc = w & 3;
  const int fro = lane & 15, hi = lane >> 4;
  const int srow4 = t >> 4;   // 0..31
  const int sslot = t & 15;   // 16B slot

#define STG32(gp, lp)                                                         \
  {                                                                           \
    _Pragma("unroll") for (int ii = 0; ii < 4; ++ii) {                        \
      const int row_ = ii * 32 + srow4;                                       \
      lds16((gp) + (size_t)row_ * 128 + ((sslot ^ (row_ & 7)) << 3),          \
            (u16*)(lp) + ii * 4096 + t * 8);                                  \
    }                                                                         \
  }
#define RDS(base, row, kslot)                                                 \
  (*(const short8*)&(base)[(size_t)(row) * 128 + (((kslot) ^ ((row) & 7)) << 3)])
// stage a 128x64 bf16 K-tile (linear layout [row][64]), 2 gloads/thread
#define TSTG(gp, lp)                                                          \
  {                                                                           \
    _Pragma("unroll") for (int q = 0; q < 2; ++q) {                           \
      const int row_ = q * 64 + (t >> 3);                                     \
      lds16((gp) + (size_t)row_ * 1024 + ((t & 7) << 3),                      \
            (u16*)(lp) + q * 4096 + t * 8);                                   \
    }                                                                         \
  }

  // ---- issue LQ stage early; drains at phase T's first counted vmcnt
  STG32(Qo + (size_t)b * 65536 + (size_t)dcol * 128, LQ);

  // ================= phase T (double-buffered staging) =================
  {
    const u16* Ag = EunT + (size_t)b * 131072;                       // [128j][1024i]
    const u16* Bg = Corig + (size_t)b * 524288 + (size_t)dcol * 1024;// [128d][1024i]
    f32x4 acc[4][2] = {};
    TSTG(Ag, sh + 32768);          // TA0
    TSTG(Bg, sh + 40960);          // TB0
    for (int k = 0; k < 16; ++k) {
      if (k < 15) {
        u16* nb = sh + 32768 + ((k + 1) & 1) * 16384;
        TSTG(Ag + (k + 1) * 64, nb);
        TSTG(Bg + (k + 1) * 64, nb + 8192);
        asm volatile("s_waitcnt vmcnt(4)" ::: "memory");  // drain tile k (+LQ @k=0)
      } else {
        asm volatile("s_waitcnt vmcnt(0)" ::: "memory");
      }
      SBAR();
      const u16* TAc = sh + 32768 + (k & 1) * 16384;
      const u16* TBc = TAc + 8192;
#pragma unroll
      for (int ks = 0; ks < 2; ++ks) {
        short8 af[4], bg[2];
        const int k8 = ks * 32 + hi * 8;
#pragma unroll
        for (int i = 0; i < 4; ++i)
          af[i] = *(const short8*)&TAc[(wr * 64 + i * 16 + fro) * 64 + k8];
#pragma unroll
        for (int jf = 0; jf < 2; ++jf)
          bg[jf] = *(const short8*)&TBc[(wc * 32 + jf * 16 + fro) * 64 + k8];
#pragma unroll
        for (int i = 0; i < 4; ++i)
#pragma unroll
          for (int jf = 0; jf < 2; ++jf)
            acc[i][jf] = __builtin_amdgcn_mfma_f32_16x16x32_bf16(
                af[i], bg[jf], acc[i][jf], 0, 0, 0);
      }
      SBAR();
    }
    // T epilogue: scale by 1/csum[j], write LT in ab-swizzled layout
    const int col = lane & 15;
    const int r4 = hi * 4;
#pragma unroll
    for (int i = 0; i < 4; ++i)
#pragma unroll
      for (int g = 0; g < 4; ++g) {
        const int j = wr * 64 + i * 16 + r4 + g;
        const float inv = 1.f / csum[b * 128 + j];
#pragma unroll
        for (int jf = 0; jf < 2; ++jf) {
          const int d = wc * 32 + jf * 16 + col;
          LT[d * 128 + (((j >> 3) ^ (d & 7)) << 3) + (j & 7)] =
              f2bf(acc[i][jf][g] * inv);
        }
      }
  }
  __syncthreads();  // LT visible; Tstage region free for LS dbuf reuse

  // ================= phase AB =================
  const u16* Sg = Sbar + (size_t)b * 131072;
  STG32(Sg, sh + 32768);
  asm volatile("s_waitcnt vmcnt(0)" ::: "memory");
  __syncthreads();

  for (int mm = 0; mm < 8; ++mm) {
    const u16* LSc = sh + 32768 + ((size_t)(mm & 1) << 14);
    u16* LSn = sh + 32768 + ((size_t)((mm + 1) & 1) << 14);
    if (mm < 7) STG32(Sg + (size_t)(mm + 1) * 16384, LSn);

    f32x4 aa[4][2] = {};
    f32x4 ab[4][2] = {};
#pragma unroll
    for (int ks = 0; ks < 4; ++ks) {
      short8 af[4], bq[2], bt[2];
#pragma unroll
      for (int i = 0; i < 4; ++i) {
        const int r = wr * 64 + i * 16 + fro;
        af[i] = RDS(LSc, r, ks * 4 + hi);
      }
#pragma unroll
      for (int j = 0; j < 2; ++j) {
        const int r = wc * 32 + j * 16 + fro;
        bq[j] = RDS(LQ, r, ks * 4 + hi);
        bt[j] = RDS(LT, r, ks * 4 + hi);
      }
#pragma unroll
      for (int i = 0; i < 4; ++i)
#pragma unroll
        for (int j = 0; j < 2; ++j) {
          aa[i][j] =
              __builtin_amdgcn_mfma_f32_16x16x32_bf16(af[i], bq[j], aa[i][j], 0, 0, 0);
          ab[i][j] =
              __builtin_amdgcn_mfma_f32_16x16x32_bf16(af[i], bt[j], ab[i][j], 0, 0, 0);
        }
    }

    const size_t obase = (size_t)b * 2097152 + (size_t)mm * 262144 + dcol;
    __syncthreads();  // drains prefetch too
#pragma unroll
    for (int i = 0; i < 4; ++i)
#pragma unroll
      for (int j = 0; j < 2; ++j)
#pragma unroll
        for (int g = 0; g < 4; ++g)
          Ls[(wr * 64 + i * 16 + hi * 4 + g) * 128 + wc * 32 + j * 16 + fro] =
              f2bf(aa[i][j][g]);
    __syncthreads();
    short8 c8[4];
#pragma unroll
    for (int it = 0; it < 4; ++it) {
      const int row = it * 32 + srow4;
      const short8 a8 = *(const short8*)&Ls[row * 128 + sslot * 8];
      c8[it] = *(const short8*)&O[obase + (size_t)row * 2048 + sslot * 8];
      short8 p2;
#pragma unroll
      for (int k = 0; k < 8; ++k)
        p2[k] = (short)f2bf(bf2f((u16)c8[it][k]) * bf2f((u16)a8[k]));
      *(short8*)&O[obase + (size_t)row * 2048 + sslot * 8 + 512] = a8;
      *(short8*)&O[obase + (size_t)row * 2048 + sslot * 8 + 1024] = p2;
    }
    __syncthreads();
#pragma unroll
    for (int i = 0; i < 4; ++i)
#pragma unroll
      for (int j = 0; j < 2; ++j)
#pragma unroll
        for (int g = 0; g < 4; ++g)
          Ls[(wr * 64 + i * 16 + hi * 4 + g) * 128 + wc * 32 + j * 16 + fro] =
              f2bf(ab[i][j][g]);
    __syncthreads();
#pragma unroll
    for (int it = 0; it < 4; ++it) {
      const int row = it * 32 + srow4;
      const short8 b8 = *(const short8*)&Ls[row * 128 + sslot * 8];
      short8 p3;
#pragma unroll
      for (int k = 0; k < 8; ++k)
        p3[k] = (short)f2bf(bf2f((u16)c8[it][k]) * bf2f((u16)b8[k]));
      *(short8*)&O[obase + (size_t)row * 2048 + sslot * 8 + 1536] = p3;
    }
    __syncthreads();
  }
#undef STG32
#undef RDS
#undef TSTG
}

// ---- prep: C fp32 -> O chunk0 = C_t bf16 (ld 2048), Corig bf16, cbias atomic
__global__ __launch_bounds__(256) void prep_C(const float* __restrict__ C,
                                              const float* __restrict__ W0,
                                              u16* __restrict__ O,
                                              u16* __restrict__ Corig,
                                              float* __restrict__ cb) {
  __shared__ float L[64][65];
  __shared__ float P[4][64];
  const int b = blockIdx.z;
  const int d0 = blockIdx.y * 64;
  const int i0 = blockIdx.x * 64;
  const int t = threadIdx.x;
  const int cx = t & 63;
  const int rb = t >> 6;
  const float* Cb = C + ((size_t)b * 512 + d0) * 1024 + i0;
  float part = 0.f;
#pragma unroll
  for (int rr = 0; rr < 16; ++rr) {
    const int r = rb * 16 + rr;
    const float v = Cb[(size_t)r * 1024 + cx];
    L[r][cx] = v;
    part = fmaf(v, W0[d0 + r], part);
    Corig[((size_t)b * 512 + d0 + r) * 1024 + i0 + cx] = f2bf(v);
  }
  P[rb][cx] = part;
  __syncthreads();
#pragma unroll
  for (int rr = 0; rr < 16; ++rr) {
    const int il = rb * 16 + rr;
    O[((size_t)b * 1024 + i0 + il) * 2048 + d0 + cx] = f2bf(L[cx][il]);
  }
  if (rb == 0)
    atomicAdd(&cb[b * 1024 + i0 + cx], P[0][cx] + P[1][cx] + P[2][cx] + P[3][cx]);
}

// ---- prep: Q -> Qmb, Qorig, qbias atomic; also converts Wr -> Wrb ----------
__global__ __launch_bounds__(256) void prep_Q(const float* __restrict__ Q,
                                              const float* __restrict__ W0,
                                              const float* __restrict__ Wr,
                                              u16* __restrict__ Qmb,
                                              u16* __restrict__ Qorig,
                                              float* __restrict__ qb,
                                              u16* __restrict__ Wrb) {
  __shared__ float L[64][65];
  __shared__ float P[4][64];
  const int b = blockIdx.z;
  const int d0 = blockIdx.y * 64;
  const int j0 = blockIdx.x * 64;
  const int t = threadIdx.x;
  const int cx = t & 63;
  const int rb = t >> 6;
  // fused cvt_wr: flat block id in [0,1024) covers Wr (512x2048 fp32)
  {
    const int fb = (blockIdx.z * 8 + blockIdx.y) * 2 + blockIdx.x;
    const int idx = fb * 256 + t;
    const float4 v = ((const float4*)Wr)[idx];
    short4v o;
    o[0] = (short)f2bf(v.x);
    o[1] = (short)f2bf(v.y);
    o[2] = (short)f2bf(v.z);
    o[3] = (short)f2bf(v.w);
    *(short4v*)&Wrb[(size_t)idx * 4] = o;
  }
  const float* Qb = Q + ((size_t)b * 512 + d0) * 128 + j0;
  float part = 0.f;
#pragma unroll
  for (int rr = 0; rr < 16; ++rr) {
    const int r = rb * 16 + rr;
    const float v = Qb[(size_t)r * 128 + cx];
    L[r][cx] = v;
    part = fmaf(v, W0[512 + d0 + r], part);
    Qorig[((size_t)b * 512 + d0 + r) * 128 + j0 + cx] = f2bf(v);
  }
  P[rb][cx] = part;
  __syncthreads();
  const float wm = W0[1024 + d0 + cx];
#pragma unroll
  for (int rr = 0; rr < 16; ++rr) {
    const int jl = rb * 16 + rr;
    Qmb[((size_t)b * 128 + j0 + jl) * 512 + d0 + cx] = f2bf(L[cx][jl] * wm);
  }
  if (rb == 0)
    atomicAdd(&qb[b * 128 + j0 + cx], P[0][cx] + P[1][cx] + P[2][cx] + P[3][cx]);
}

extern "C" void kernel_launch(void* const* d_in, const int* in_sizes, int n_in,
                              void* d_out, int out_size, void* d_ws, size_t ws_size,
                              hipStream_t stream) {
  (void)in_sizes; (void)n_in; (void)out_size;
  const float* C = (const float*)d_in[0];
  const float* Q = (const float*)d_in[1];
  const float* cm = (const float*)d_in[2];
  const float* qm = (const float*)d_in[3];
  const float* W0 = (const float*)d_in[4];
  const float* Wr = (const float*)d_in[5];
  float* out = (float*)d_out;

  if (ws_size < 405078016ull) return;  // ~386 MiB scratch

  char* p = (char*)d_ws;
  u16* O     = (u16*)(p);                    // (B,1024,2048) bf16 [C_t|A|C*A|C*Bm]
  u16* Corig = (u16*)(p + 268435456ull);     // (B,512,1024) bf16
  u16* Qmb   = (u16*)(p + 335544320ull);     // (B,128,512)  bf16
  u16* Qorig = (u16*)(p + 343932928ull);     // (B,512,128)  bf16
  u16* EunT  = (u16*)(p + 360710144ull);     // (B,128,1024) bf16 unnorm col-exp^T
  u16* Sbar  = (u16*)(p + 377487360ull);     // (B,1024,128) bf16
  u16* Wrb   = (u16*)(p + 402653184ull);     // (512,2048)   bf16
  float* cb  = (float*)(p + 404750336ull);   // (B,1024)
  float* qb  = (float*)(p + 405012480ull);   // (B,128)
  float* csum= (float*)(p + 405045248ull);   // (B,128)

  (void)hipFuncSetAttribute((const void*)gemm8b,
                            hipFuncAttributeMaxDynamicSharedMemorySize, 163840);
  (void)hipFuncSetAttribute((const void*)gemm_tab,
                            hipFuncAttributeMaxDynamicSharedMemorySize, 163840);
  (void)hipMemsetAsync(cb, 0, 327680, stream);  // cb + qb + csum contiguous

  prep_C<<<dim3(16, 8, 64), dim3(256), 0, stream>>>(C, W0, O, Corig, cb);
  prep_Q<<<dim3(2, 8, 64), dim3(256), 0, stream>>>(Q, W0, Wr, Qmb, Qorig, qb,
                                                   Wrb);

  // S-GEMM + fused row softmax + transposed unnormalized col-exp (XCD-swz)
  gemm_s<<<dim3(512), dim3(256), 0, stream>>>(O, Qmb, cb, qb, cm, qm,
                                              Sbar, EunT, csum);

  // merged T-GEMM + A/Bm GEMM (XCD-swz): chunks 1,2,3 of O
  gemm_tab<<<dim3(256), dim3(512), 163840, stream>>>(EunT, Corig, csum,
                                                     Sbar, Qorig, O);

  // R = Wr @ out^T : flat M=512, N=65536, K=2048; 16-wave 256^2
  gemm8b<<<dim3(512), dim3(1024), 163840, stream>>>(Wrb, O, out);
}